// Round 5
// baseline (2716.105 us; speedup 1.0000x reference)
//
#include <hip/hip_runtime.h>

#define NA 50000
#define NB 50000
#define NN 50000
#define CDIM 128
#define EDGES 800000
#define SS 8
#define INDIM 64
#define HDIM 64
#define NBASES 8
#define NBUCK 98
#define BSH 9
#define NCHUNK 25          // src chunks of 2048 rows (512 KB bf16) for L2-windowed gather
#define CSH 11
#define NKEY (512 * NCHUNK)   // 12800 counting-sort keys per dst bucket
#define RPSTR (NN * NCHUNK + 1)
#define BNDN (32 * NCHUNK + 1)   // 801 per-block boundary entries

#define RROWS 32
#define USTR 136   // ushort stride (pad) for bf16 U/V tiles
#define SSTR 129   // float stride for acc staging

typedef __attribute__((ext_vector_type(8))) short bf16x8;
typedef __attribute__((ext_vector_type(4))) float f32x4;

// ---------------------------------------------------------------------------
// Workspace layout (4-byte element offsets) — re-audited:
//   0         col      [3*E]              int    -> 2400000
//   2400000   rowptr   [3*(NN*25+1)]      int    -> 6150003
//   6150016   bcnt     [3*98]             int
//   6150320   boff     [3*99]             int
//   6150624   bcur     [3*98]             int
//   6150928   xa_buf   [NA*128]           float  -> 12550928
//             (buf[3*E] = 2.4M uints aliases xa_buf head; dead before
//              layer-0 fuse_a writes xa_buf)
//   12550928  xb_buf   [NB*128]           float  -> 18950928
//   18950928  Wbf      ushort[98304] = 49152 words -> 19000080
//   19000080  coeffs   [24] float (pad to 19000112)
//   19000112  xa_bf0   ushort[(NN+1)*128] = 3200064 words -> 22200176
//   22200176  xb_bf0   -> 25400240
//   25400240  xa_bf1   -> 28600304
//   28600304  xb_bf1   -> 31800368   (~127 MB total)
// ---------------------------------------------------------------------------

__device__ __forceinline__ unsigned short f2bf(float f) {
    unsigned u = __float_as_uint(f);
    return (unsigned short)((u + 0x7FFFu + ((u >> 16) & 1u)) >> 16);
}

// Schema GCN + coefficient computation. One block, 512 threads.
__global__ __launch_bounds__(512) void schema_kernel(
    const float* __restrict__ schema_x, const int* __restrict__ sei,
    const float* __restrict__ preW, const float* __restrict__ preb,
    const float* __restrict__ gcnW, const float* __restrict__ gcnb,
    const float* __restrict__ coW, const float* __restrict__ cob,
    float* __restrict__ out_sf, float* __restrict__ out_ori,
    float* __restrict__ coeffs)
{
    __shared__ float h[SS][HDIM];
    __shared__ float xw[SS][HDIM];
    __shared__ float sf[SS][HDIM];
    __shared__ float deg[SS];
    __shared__ float nrm[32];
    __shared__ int es[32], ed[32];

    int t = threadIdx.x;
    int i = t >> 6, j = t & 63;

    float acc = preb[j];
    for (int k = 0; k < INDIM; k++) acc += schema_x[i * INDIM + k] * preW[j * INDIM + k];
    h[i][j] = acc;
    out_ori[i * HDIM + j] = acc;
    if (t < SS) deg[t] = 0.0f;
    __syncthreads();

    if (t < 32) {
        int s, d;
        if (t < 24) { s = sei[t]; d = sei[24 + t]; }
        else        { s = t - 24; d = t - 24; }
        es[t] = s; ed[t] = d;
        atomicAdd(&deg[d], 1.0f);
    }
    __syncthreads();
    if (t < 32) {
        nrm[t] = rsqrtf(fmaxf(deg[es[t]], 1e-12f)) * rsqrtf(fmaxf(deg[ed[t]], 1e-12f));
    }
    float a2 = 0.0f;
    for (int k = 0; k < HDIM; k++) a2 += h[i][k] * gcnW[j * HDIM + k];
    xw[i][j] = a2;
    __syncthreads();

    float o = gcnb[j];
    for (int e = 0; e < 32; e++) {
        if (ed[e] == i) o += xw[es[e]][j] * nrm[e];
    }
    float s = fmaxf(o, 0.0f);
    sf[i][j] = s;
    out_sf[i * HDIM + j] = s;
    __syncthreads();

    if (t < 24) {
        int ty = t >> 3, ii = t & 7;
        int srow = (ty == 1) ? 1 : 0;
        int drow = (ty == 0) ? 1 : 0;
        float a = cob[ii];
        for (int k = 0; k < HDIM; k++) a += sf[srow][k] * coW[ii * (2 * HDIM) + k];
        for (int k = 0; k < HDIM; k++) a += sf[drow][k] * coW[ii * (2 * HDIM) + HDIM + k];
        coeffs[ty * 8 + ii] = a;
    }
}

// W in bf16, row-major [mat][j][k] (B-operand needs contiguous k per row)
__global__ __launch_bounds__(256) void build_w_kernel(
    const float* __restrict__ bases, const float* __restrict__ coeffs,
    unsigned short* __restrict__ Wbf)
{
    int idx = blockIdx.x * blockDim.x + threadIdx.x;   // < 6*16384
    int lt = idx >> 14;
    int jk = idx & 16383;
    int l = lt / 3, ty = lt % 3;
    float acc = 0.0f;
#pragma unroll
    for (int i = 0; i < NBASES; i++)
        acc += coeffs[ty * 8 + i] * bases[((size_t)(l * NBASES + i) << 14) + jk];
    Wbf[idx] = f2bf(acc);
}

__global__ __launch_bounds__(256) void tobf16_kernel(
    const float* __restrict__ in, unsigned short* __restrict__ out, int n)
{
    int i = (blockIdx.x * 256 + threadIdx.x) * 4;
    if (i >= n) return;
    float4 f = *(const float4*)(in + i);
    ushort4 o;
    o.x = f2bf(f.x); o.y = f2bf(f.y); o.z = f2bf(f.z); o.w = f2bf(f.w);
    *(ushort4*)(out + i) = o;
}

__global__ __launch_bounds__(256) void zero_rows_kernel(
    unsigned short* a0, unsigned short* b0, unsigned short* a1, unsigned short* b1)
{
    int t = threadIdx.x;
    int tab = t >> 6, w = t & 63;
    unsigned short* p = (tab == 0) ? a0 : (tab == 1) ? b0 : (tab == 2) ? a1 : b1;
    ((unsigned*)(p + (size_t)NN * CDIM))[w] = 0u;
}

// ---------------- locality-aware CSR build ----------------------------------

__global__ __launch_bounds__(256) void bucket_count_kernel(
    const int* __restrict__ ab, const int* __restrict__ ba,
    const int* __restrict__ aa, int* __restrict__ bcnt)
{
    __shared__ int h[NBUCK];
    int t = threadIdx.x;
    int ty = blockIdx.y;
    const int* ei = (ty == 0) ? ab : (ty == 1) ? ba : aa;
    if (t < NBUCK) h[t] = 0;
    __syncthreads();
    int cb = blockIdx.x * 4096;
    int en = min(cb + 4096, EDGES);
    for (int e = cb + t; e < en; e += 256)
        atomicAdd(&h[ei[EDGES + e] >> BSH], 1);
    __syncthreads();
    if (t < NBUCK) atomicAdd(&bcnt[ty * NBUCK + t], h[t]);
}

__global__ __launch_bounds__(32) void bucket_scan_kernel(
    const int* __restrict__ bcnt, int* __restrict__ boff, int* __restrict__ bcur)
{
    int t = threadIdx.x;
    if (t < 3) {
        int run = 0;
        for (int i = 0; i < NBUCK; i++) {
            int c = bcnt[t * NBUCK + i];
            boff[t * (NBUCK + 1) + i] = run;
            bcur[t * NBUCK + i] = run;
            run += c;
        }
        boff[t * (NBUCK + 1) + NBUCK] = run;
    }
}

__global__ __launch_bounds__(256) void bucket_partition_kernel(
    const int* __restrict__ ab, const int* __restrict__ ba,
    const int* __restrict__ aa, int* __restrict__ bcur,
    unsigned* __restrict__ buf)
{
    __shared__ int h[NBUCK];
    __shared__ int basearr[NBUCK];
    __shared__ int cur[NBUCK];
    int t = threadIdx.x;
    int ty = blockIdx.y;
    const int* ei = (ty == 0) ? ab : (ty == 1) ? ba : aa;
    if (t < NBUCK) h[t] = 0;
    __syncthreads();
    int cb = blockIdx.x * 4096;
    int en = min(cb + 4096, EDGES);
    for (int e = cb + t; e < en; e += 256)
        atomicAdd(&h[ei[EDGES + e] >> BSH], 1);
    __syncthreads();
    if (t < NBUCK) {
        basearr[t] = atomicAdd(&bcur[ty * NBUCK + t], h[t]);
        cur[t] = 0;
    }
    __syncthreads();
    for (int e = cb + t; e < en; e += 256) {
        int src = ei[e], dst = ei[EDGES + e];
        int b = dst >> BSH;
        int r = atomicAdd(&cur[b], 1);
        buf[(size_t)ty * EDGES + basearr[b] + r] =
            ((unsigned)(dst & 511) << 16) | (unsigned)src;
    }
}

// Counting sort within each dst bucket by key (dst&511, src>>CSH): produces
// col[] sorted by (row, src-chunk) and per-(row,chunk) rowptr boundaries.
__global__ __launch_bounds__(256) void bucket_scatter_kernel(
    const unsigned* __restrict__ buf, const int* __restrict__ boff,
    int* __restrict__ rowptr, int* __restrict__ col)
{
    __shared__ int cnt[NKEY];      // 12800 * 4 = 51.2 KB
    __shared__ int part[256];
    int t = threadIdx.x;
    int b = blockIdx.x, ty = blockIdx.y;
    int nstart = boff[ty * (NBUCK + 1) + b];
    int nend   = boff[ty * (NBUCK + 1) + b + 1];
    int n = nend - nstart;
    for (int k = t; k < NKEY; k += 256) cnt[k] = 0;
    __syncthreads();
    const unsigned* bb = buf + (size_t)ty * EDGES + nstart;
    for (int i = t; i < n; i += 256) {
        unsigned pk = bb[i];
        int key = (int)(pk >> 16) * NCHUNK + (int)((pk & 0xFFFFu) >> CSH);
        atomicAdd(&cnt[key], 1);
    }
    __syncthreads();
    // scan: 50 keys per thread (= exactly 2 rows of 25 chunks)
    const int KPT = NKEY / 256;    // 50
    int k0 = t * KPT;
    int lc[KPT];
    int lsum = 0;
#pragma unroll
    for (int j = 0; j < KPT; j++) { lc[j] = cnt[k0 + j]; lsum += lc[j]; }
    part[t] = lsum;
    __syncthreads();
    for (int off2 = 1; off2 < 256; off2 <<= 1) {
        int v = (t >= off2) ? part[t - off2] : 0;
        __syncthreads();
        part[t] += v;
        __syncthreads();
    }
    int run = part[t] - lsum;      // exclusive prefix of this thread's key range
    // write back exclusive prefixes + rowptr entries
    {
        int row_in_b = k0 / NCHUNK;          // = 2t
        int ch = k0 - row_in_b * NCHUNK;     // = 0
        int rowg = (b << BSH) + row_in_b;
        size_t rpbase = (size_t)ty * RPSTR;
#pragma unroll
        for (int j = 0; j < KPT; j++) {
            cnt[k0 + j] = run;
            if (rowg < NN)
                rowptr[rpbase + (size_t)rowg * NCHUNK + ch] = nstart + run;
            run += lc[j];
            ch++;
            if (ch == NCHUNK) { ch = 0; rowg++; }
        }
        if (b == NBUCK - 1 && t == 255)
            rowptr[rpbase + (size_t)NN * NCHUNK] = EDGES;
    }
    __syncthreads();
    int* cc = col + (size_t)ty * EDGES + nstart;
    for (int i = t; i < n; i += 256) {
        unsigned pk = bb[i];
        int key = (int)(pk >> 16) * NCHUNK + (int)((pk & 0xFFFFu) >> CSH);
        int r = atomicAdd(&cnt[key], 1);
        cc[r] = (int)(pk & 0xFFFFu);
    }
}

// ---------------- fused gather + MFMA matmul + LN -> ReLU -------------------

// Chunk-major windowed sweep with batched, branch-free common path:
// per chunk, 8 rows' segments (pad-2: one slot per 32-lane half) issue
// 8 col + 8 uint2 loads back-to-back (MLP ~8); segments >2 edges (P~2.6%)
// go through a wave-uniform fallback AFTER the batch. Boundaries come from
// LDS (bnd), staged once per CSR by the caller.
__device__ __forceinline__ void sweep_store(
    const unsigned short* __restrict__ xsrc,
    const int* __restrict__ col, const float* __restrict__ xdst,
    const int* __restrict__ bnd,
    unsigned short* __restrict__ Obf,
    int base, int wv, int half, int off)
{
    float4 g[8];
#pragma unroll
    for (int rr = 0; rr < 8; rr++) g[rr] = make_float4(0.f, 0.f, 0.f, 0.f);

    for (int c = 0; c < NCHUNK; c++) {
        int cs[8];
        unsigned fb = 0;
#pragma unroll
        for (int rr = 0; rr < 8; rr++) {
            int r = rr * 4 + wv;
            int s = bnd[r * NCHUNK + c];
            int e = bnd[r * NCHUNK + c + 1];
            int sl = s + half;
            int cc = col[min(sl, EDGES - 1)];
            cs[rr] = (sl < e) ? cc : NN;
            fb |= (e - s > 2) ? (1u << rr) : 0u;
        }
        uint2 v[8];
#pragma unroll
        for (int rr = 0; rr < 8; rr++)
            v[rr] = *(const uint2*)(xsrc + (size_t)cs[rr] * CDIM + off);
#pragma unroll
        for (int rr = 0; rr < 8; rr++) {
            g[rr].x += __uint_as_float(v[rr].x << 16);
            g[rr].y += __uint_as_float(v[rr].x & 0xffff0000u);
            g[rr].z += __uint_as_float(v[rr].y << 16);
            g[rr].w += __uint_as_float(v[rr].y & 0xffff0000u);
        }
        fb = (unsigned)__builtin_amdgcn_readfirstlane((int)fb);
        if (fb) {
#pragma unroll 1
            for (int rr = 0; rr < 8; rr++) {
                if (!((fb >> rr) & 1u)) continue;
                int r = rr * 4 + wv;
                int s = bnd[r * NCHUNK + c] + 2;
                int e = bnd[r * NCHUNK + c + 1];
                for (int b0 = s; b0 < e; b0 += 2) {
                    int sl = b0 + half;
                    int cc = col[min(sl, e - 1)];
                    int id = (sl < e) ? cc : NN;
                    uint2 vv = *(const uint2*)(xsrc + (size_t)id * CDIM + off);
                    g[rr].x += __uint_as_float(vv.x << 16);
                    g[rr].y += __uint_as_float(vv.x & 0xffff0000u);
                    g[rr].z += __uint_as_float(vv.y << 16);
                    g[rr].w += __uint_as_float(vv.y & 0xffff0000u);
                }
            }
        }
    }

#pragma unroll
    for (int rr = 0; rr < 8; rr++) {
        int r = rr * 4 + wv;
        int row = base + r;
        float4 gg = g[rr];
        gg.x += __shfl_xor(gg.x, 32, 64);
        gg.y += __shfl_xor(gg.y, 32, 64);
        gg.z += __shfl_xor(gg.z, 32, 64);
        gg.w += __shfl_xor(gg.w, 32, 64);
        if (half == 0) {
            ushort4 o = make_ushort4(0, 0, 0, 0);
            if (row < NN) {
                int deg = bnd[r * NCHUNK + NCHUNK] - bnd[r * NCHUNK];
                float inv = 1.0f / (float)max(deg, 1);
                const float4 xv = *(const float4*)(xdst + (size_t)row * CDIM + off);
                o.x = f2bf(gg.x * inv + xv.x);
                o.y = f2bf(gg.y * inv + xv.y);
                o.z = f2bf(gg.z * inv + xv.z);
                o.w = f2bf(gg.w * inv + xv.w);
            }
            *(ushort4*)&Obf[r * USTR + off] = o;
        }
    }
}

// b-side: mean(bf x_a) + x_b -> bf16 U; U @ W^T (MFMA) + bias -> LN -> ReLU
__global__ __launch_bounds__(256, 6) void fuse_b_kernel(
    const unsigned short* __restrict__ xsrc, const float* __restrict__ xdst,
    const int* __restrict__ rowptr, const int* __restrict__ col,
    const unsigned short* __restrict__ Wbf, const float* __restrict__ bias,
    const float* __restrict__ lnw, const float* __restrict__ lnb,
    float* __restrict__ xnext, unsigned short* __restrict__ xnext_bf)
{
    __shared__ float4 smraw[1032];   // max(RROWS*USTR*2, RROWS*SSTR*4) = 16512 B
    __shared__ int bnd[BNDN];
    unsigned short* Ubf = (unsigned short*)smraw;
    float* stage = (float*)smraw;
    int t = threadIdx.x;
    int base = blockIdx.x * RROWS;
    int wv = t >> 6;
    int lane = t & 63;
    int half = lane >> 5, cl = lane & 31;
    int off = cl << 2;

    for (int i = t; i < BNDN; i += 256)
        bnd[i] = rowptr[min(base * NCHUNK + i, NN * NCHUNK)];
    __syncthreads();

    sweep_store(xsrc, col, xdst, bnd, Ubf, base, wv, half, off);
    __syncthreads();

    // MFMA: wave wv -> N-tiles {2wv, 2wv+1}, M-tiles {0,1}
    int qd = lane >> 4;
    int ln16 = lane & 15;
    f32x4 acc00 = {0.f,0.f,0.f,0.f}, acc01 = acc00, acc10 = acc00, acc11 = acc00;
#pragma unroll
    for (int ks = 0; ks < 4; ks++) {
        int koff = ks * 32 + qd * 8;
        bf16x8 a0 = *(const bf16x8*)&Ubf[(ln16) * USTR + koff];
        bf16x8 a1 = *(const bf16x8*)&Ubf[(16 + ln16) * USTR + koff];
        bf16x8 b0 = *(const bf16x8*)&Wbf[(size_t)((2 * wv + 0) * 16 + ln16) * CDIM + koff];
        bf16x8 b1 = *(const bf16x8*)&Wbf[(size_t)((2 * wv + 1) * 16 + ln16) * CDIM + koff];
        acc00 = __builtin_amdgcn_mfma_f32_16x16x32_bf16(a0, b0, acc00, 0, 0, 0);
        acc01 = __builtin_amdgcn_mfma_f32_16x16x32_bf16(a0, b1, acc01, 0, 0, 0);
        acc10 = __builtin_amdgcn_mfma_f32_16x16x32_bf16(a1, b0, acc10, 0, 0, 0);
        acc11 = __builtin_amdgcn_mfma_f32_16x16x32_bf16(a1, b1, acc11, 0, 0, 0);
    }
    __syncthreads();   // all MFMA reads of Ubf done before stage overwrites it
    // C/D layout: col = lane&15 (in tile), row = quad*4 + reg
    {
        int c0 = (2 * wv + 0) * 16 + ln16;
        int c1 = (2 * wv + 1) * 16 + ln16;
#pragma unroll
        for (int i = 0; i < 4; i++) {
            int r0 = qd * 4 + i;
            stage[r0 * SSTR + c0] = acc00[i];
            stage[r0 * SSTR + c1] = acc01[i];
            stage[(16 + r0) * SSTR + c0] = acc10[i];
            stage[(16 + r0) * SSTR + c1] = acc11[i];
        }
    }
    __syncthreads();

    float b0v = bias[lane], b1v = bias[lane + 64];
    float lw0 = lnw[lane], lw1 = lnw[lane + 64];
    float lb0 = lnb[lane], lb1 = lnb[lane + 64];
    for (int rr = 0; rr < RROWS / 4; rr++) {
        int r = rr * 4 + wv;
        int row = base + r;
        if (row >= NN) continue;
        float v0 = stage[r * SSTR + lane] + b0v;
        float v1 = stage[r * SSTR + lane + 64] + b1v;
        float s = v0 + v1, s2 = v0 * v0 + v1 * v1;
#pragma unroll
        for (int o2 = 32; o2 > 0; o2 >>= 1) {
            s  += __shfl_xor(s,  o2, 64);
            s2 += __shfl_xor(s2, o2, 64);
        }
        float mu = s * (1.0f / CDIM);
        float var = s2 * (1.0f / CDIM) - mu * mu;
        float rs = rsqrtf(var + 1e-5f);
        float o0 = fmaxf((v0 - mu) * rs * lw0 + lb0, 0.0f);
        float o1 = fmaxf((v1 - mu) * rs * lw1 + lb1, 0.0f);
        size_t oi = (size_t)row * CDIM;
        xnext[oi + lane] = o0;
        xnext[oi + lane + 64] = o1;
        if (xnext_bf) {
            xnext_bf[oi + lane] = f2bf(o0);
            xnext_bf[oi + lane + 64] = f2bf(o1);
        }
    }
}

// a-side: U = mean_ba(bf x_b)+x_a, V = mean_aa(bf x_a)+x_a;
// out = U@W1^T + V@W2^T + b1 + b2 (MFMA) -> LN -> ReLU
// Two sequential single-table chunk sweeps keep the live window at 512 KB.
__global__ __launch_bounds__(256, 6) void fuse_a_kernel(
    const unsigned short* __restrict__ xsrc1, const int* __restrict__ rowptr1, const int* __restrict__ col1,
    const unsigned short* __restrict__ xsrc2, const int* __restrict__ rowptr2, const int* __restrict__ col2,
    const float* __restrict__ xdst,
    const unsigned short* __restrict__ W1bf, const unsigned short* __restrict__ W2bf,
    const float* __restrict__ bias1, const float* __restrict__ bias2,
    const float* __restrict__ lnw, const float* __restrict__ lnb,
    float* __restrict__ xnext, unsigned short* __restrict__ xnext_bf)
{
    __shared__ float4 smraw[1088];   // max(2*RROWS*USTR*2, RROWS*SSTR*4) = 17408 B
    __shared__ int bnd[BNDN];
    unsigned short* Ubf = (unsigned short*)smraw;
    unsigned short* Vbf = Ubf + RROWS * USTR;
    float* stage = (float*)smraw;
    int t = threadIdx.x;
    int base = blockIdx.x * RROWS;
    int wv = t >> 6;
    int lane = t & 63;
    int half = lane >> 5, cl = lane & 31;
    int off = cl << 2;

    for (int i = t; i < BNDN; i += 256)
        bnd[i] = rowptr1[min(base * NCHUNK + i, NN * NCHUNK)];
    __syncthreads();
    sweep_store(xsrc1, col1, xdst, bnd, Ubf, base, wv, half, off);
    __syncthreads();

    for (int i = t; i < BNDN; i += 256)
        bnd[i] = rowptr2[min(base * NCHUNK + i, NN * NCHUNK)];
    __syncthreads();
    sweep_store(xsrc2, col2, xdst, bnd, Vbf, base, wv, half, off);
    __syncthreads();

    int qd = lane >> 4;
    int ln16 = lane & 15;
    f32x4 acc00 = {0.f,0.f,0.f,0.f}, acc01 = acc00, acc10 = acc00, acc11 = acc00;
#pragma unroll
    for (int ks = 0; ks < 4; ks++) {
        int koff = ks * 32 + qd * 8;
        bf16x8 aU0 = *(const bf16x8*)&Ubf[(ln16) * USTR + koff];
        bf16x8 aU1 = *(const bf16x8*)&Ubf[(16 + ln16) * USTR + koff];
        bf16x8 aV0 = *(const bf16x8*)&Vbf[(ln16) * USTR + koff];
        bf16x8 aV1 = *(const bf16x8*)&Vbf[(16 + ln16) * USTR + koff];
        size_t wrow0 = (size_t)((2 * wv + 0) * 16 + ln16) * CDIM + koff;
        size_t wrow1 = (size_t)((2 * wv + 1) * 16 + ln16) * CDIM + koff;
        bf16x8 b10 = *(const bf16x8*)&W1bf[wrow0];
        bf16x8 b11 = *(const bf16x8*)&W1bf[wrow1];
        bf16x8 b20 = *(const bf16x8*)&W2bf[wrow0];
        bf16x8 b21 = *(const bf16x8*)&W2bf[wrow1];
        acc00 = __builtin_amdgcn_mfma_f32_16x16x32_bf16(aU0, b10, acc00, 0, 0, 0);
        acc01 = __builtin_amdgcn_mfma_f32_16x16x32_bf16(aU0, b11, acc01, 0, 0, 0);
        acc10 = __builtin_amdgcn_mfma_f32_16x16x32_bf16(aU1, b10, acc10, 0, 0, 0);
        acc11 = __builtin_amdgcn_mfma_f32_16x16x32_bf16(aU1, b11, acc11, 0, 0, 0);
        acc00 = __builtin_amdgcn_mfma_f32_16x16x32_bf16(aV0, b20, acc00, 0, 0, 0);
        acc01 = __builtin_amdgcn_mfma_f32_16x16x32_bf16(aV0, b21, acc01, 0, 0, 0);
        acc10 = __builtin_amdgcn_mfma_f32_16x16x32_bf16(aV1, b20, acc10, 0, 0, 0);
        acc11 = __builtin_amdgcn_mfma_f32_16x16x32_bf16(aV1, b21, acc11, 0, 0, 0);
    }
    __syncthreads();   // all MFMA reads of Ubf/Vbf done before stage overwrites them
    {
        int c0 = (2 * wv + 0) * 16 + ln16;
        int c1 = (2 * wv + 1) * 16 + ln16;
#pragma unroll
        for (int i = 0; i < 4; i++) {
            int r0 = qd * 4 + i;
            stage[r0 * SSTR + c0] = acc00[i];
            stage[r0 * SSTR + c1] = acc01[i];
            stage[(16 + r0) * SSTR + c0] = acc10[i];
            stage[(16 + r0) * SSTR + c1] = acc11[i];
        }
    }
    __syncthreads();

    float b0v = bias1[lane] + bias2[lane];
    float b1v = bias1[lane + 64] + bias2[lane + 64];
    float lw0 = lnw[lane], lw1 = lnw[lane + 64];
    float lb0 = lnb[lane], lb1 = lnb[lane + 64];
    for (int rr = 0; rr < RROWS / 4; rr++) {
        int r = rr * 4 + wv;
        int row = base + r;
        if (row >= NN) continue;
        float v0 = stage[r * SSTR + lane] + b0v;
        float v1 = stage[r * SSTR + lane + 64] + b1v;
        float s = v0 + v1, s2 = v0 * v0 + v1 * v1;
#pragma unroll
        for (int o2 = 32; o2 > 0; o2 >>= 1) {
            s  += __shfl_xor(s,  o2, 64);
            s2 += __shfl_xor(s2, o2, 64);
        }
        float mu = s * (1.0f / CDIM);
        float var = s2 * (1.0f / CDIM) - mu * mu;
        float rs = rsqrtf(var + 1e-5f);
        float o0 = fmaxf((v0 - mu) * rs * lw0 + lb0, 0.0f);
        float o1 = fmaxf((v1 - mu) * rs * lw1 + lb1, 0.0f);
        size_t oi = (size_t)row * CDIM;
        xnext[oi + lane] = o0;
        xnext[oi + lane + 64] = o1;
        if (xnext_bf) {
            xnext_bf[oi + lane] = f2bf(o0);
            xnext_bf[oi + lane + 64] = f2bf(o1);
        }
    }
}

extern "C" void kernel_launch(void* const* d_in, const int* in_sizes, int n_in,
                              void* d_out, int out_size, void* d_ws, size_t ws_size,
                              hipStream_t stream)
{
    const float* x_a      = (const float*)d_in[0];
    const float* x_b      = (const float*)d_in[1];
    const float* schema_x = (const float*)d_in[2];
    const int*   e_ab     = (const int*)d_in[3];
    const int*   e_ba     = (const int*)d_in[4];
    const int*   e_aa     = (const int*)d_in[5];
    const int*   sei      = (const int*)d_in[6];
    const float* preW     = (const float*)d_in[7];
    const float* preb     = (const float*)d_in[8];
    const float* gcnW     = (const float*)d_in[9];
    const float* gcnb     = (const float*)d_in[10];
    const float* coW      = (const float*)d_in[11];
    const float* cob      = (const float*)d_in[12];
    const float* bases    = (const float*)d_in[13];
    const float* sbias    = (const float*)d_in[14];
    const float* lnw      = (const float*)d_in[15];
    const float* lnb      = (const float*)d_in[16];

    float* out     = (float*)d_out;
    float* out_xa  = out;
    float* out_xb  = out + 6400000;
    float* out_sf  = out + 12800000;
    float* out_ori = out + 12800512;

    float* ws = (float*)d_ws;
    int*      col    = (int*)ws;
    int*      rowptr = (int*)(ws + 2400000);
    int*      bcnt   = (int*)(ws + 6150016);
    int*      boff   = (int*)(ws + 6150320);
    int*      bcur   = (int*)(ws + 6150624);
    float* xa_buf = ws + 6150928;
    unsigned* buf = (unsigned*)xa_buf;     // aliases xa_buf head; dead before layer-0 fuse_a
    float* xb_buf = ws + 12550928;
    unsigned short* Wbf = (unsigned short*)(ws + 18950928);
    float* coeffs = ws + 19000080;
    unsigned short* xa_bf0 = (unsigned short*)(ws + 19000112);
    unsigned short* xb_bf0 = (unsigned short*)(ws + 22200176);
    unsigned short* xa_bf1 = (unsigned short*)(ws + 25400240);
    unsigned short* xb_bf1 = (unsigned short*)(ws + 28600304);

    schema_kernel<<<1, 512, 0, stream>>>(schema_x, sei, preW, preb, gcnW, gcnb,
                                         coW, cob, out_sf, out_ori, coeffs);
    build_w_kernel<<<384, 256, 0, stream>>>(bases, coeffs, Wbf);

    tobf16_kernel<<<(NA * CDIM / 4 + 255) / 256, 256, 0, stream>>>(x_a, xa_bf0, NA * CDIM);
    tobf16_kernel<<<(NB * CDIM / 4 + 255) / 256, 256, 0, stream>>>(x_b, xb_bf0, NB * CDIM);
    zero_rows_kernel<<<1, 256, 0, stream>>>(xa_bf0, xb_bf0, xa_bf1, xb_bf1);

    hipMemsetAsync(bcnt, 0, 3 * NBUCK * sizeof(int), stream);
    dim3 cgrid((EDGES + 4095) / 4096, 3);
    bucket_count_kernel<<<cgrid, 256, 0, stream>>>(e_ab, e_ba, e_aa, bcnt);
    bucket_scan_kernel<<<1, 32, 0, stream>>>(bcnt, boff, bcur);
    bucket_partition_kernel<<<cgrid, 256, 0, stream>>>(e_ab, e_ba, e_aa, bcur, buf);
    dim3 sgrid(NBUCK, 3);
    bucket_scatter_kernel<<<sgrid, 256, 0, stream>>>(buf, boff, rowptr, col);

    const int* rp_ab = rowptr;
    const int* rp_ba = rowptr + RPSTR;
    const int* rp_aa = rowptr + 2 * RPSTR;
    const int* col_ab = col;
    const int* col_ba = col + EDGES;
    const int* col_aa = col + 2 * EDGES;

    const int fgrid = (NN + RROWS - 1) / RROWS;   // 1563

    for (int l = 0; l < 2; l++) {
        const float* xa_cur = (l == 0) ? x_a : xa_buf;
        const float* xb_cur = (l == 0) ? x_b : xb_buf;
        const unsigned short* xa_bf = (l == 0) ? xa_bf0 : xa_bf1;
        const unsigned short* xb_bf = (l == 0) ? xb_bf0 : xb_bf1;
        const unsigned short* Wab = Wbf + (size_t)(l * 3 + 0) * 16384;
        const unsigned short* Wba = Wbf + (size_t)(l * 3 + 1) * 16384;
        const unsigned short* Waa = Wbf + (size_t)(l * 3 + 2) * 16384;
        float* xa_nxt = (l == 0) ? xa_buf : out_xa;
        float* xb_nxt = (l == 0) ? xb_buf : out_xb;
        unsigned short* xa_nbf = (l == 0) ? xa_bf1 : nullptr;
        unsigned short* xb_nbf = (l == 0) ? xb_bf1 : nullptr;

        fuse_b_kernel<<<fgrid, 256, 0, stream>>>(
            xa_bf, xb_cur, rp_ab, col_ab, Wab,
            sbias + (size_t)(l * 3 + 0) * 128,
            lnw + (size_t)(l * 2 + 1) * 128, lnb + (size_t)(l * 2 + 1) * 128,
            xb_nxt, xb_nbf);
        fuse_a_kernel<<<fgrid, 256, 0, stream>>>(
            xb_bf, rp_ba, col_ba, xa_bf, rp_aa, col_aa, xa_cur,
            Wba, Waa,
            sbias + (size_t)(l * 3 + 1) * 128, sbias + (size_t)(l * 3 + 2) * 128,
            lnw + (size_t)(l * 2 + 0) * 128, lnb + (size_t)(l * 2 + 0) * 128,
            xa_nxt, xa_nbf);
    }
}

// Round 6
// 1294.117 us; speedup vs baseline: 2.0988x; 2.0988x over previous
//
#include <hip/hip_runtime.h>

#define NA 50000
#define NB 50000
#define NN 50000
#define CDIM 128
#define EDGES 800000
#define SS 8
#define INDIM 64
#define HDIM 64
#define NBASES 8
#define NBUCK 98
#define BSH 9
#define NCHUNK 25          // src chunks of 2048 rows (512 KB bf16) for L2-windowed gather
#define CSH 11
#define NKEY (512 * NCHUNK)   // 12800 counting-sort keys per dst bucket
#define RPSTR (NN * NCHUNK + 1)
#define BNDN (32 * NCHUNK + 1)   // 801 per-block boundary entries

#define RROWS 32
#define USTR 136   // ushort stride (pad) for bf16 U/V tiles
#define SSTR 129   // float stride for acc staging

typedef __attribute__((ext_vector_type(8))) short bf16x8;
typedef __attribute__((ext_vector_type(4))) float f32x4;

// ---------------------------------------------------------------------------
// Workspace layout (4-byte element offsets) — audited:
//   0         col      [3*E]              int    -> 2400000
//   2400000   rowptr   [3*(NN*25+1)]      int    -> 6150003
//   6150016   bcnt / 6150320 boff / 6150624 bcur
//   6150928   xa_buf   [NA*128] float  -> 12550928   (buf aliases head; dead
//                                                     before layer-0 fuse_a)
//   12550928  xb_buf   -> 18950928
//   18950928  Wbf      ushort[98304] = 49152 words -> 19000080
//   19000080  coeffs   [24] float (pad to 19000112)
//   19000112  xa_bf0   ushort[(NN+1)*128] = 3200064 words -> 22200176
//   22200176  xb_bf0   -> 25400240
//   25400240  xa_bf1   -> 28600304
//   28600304  xb_bf1   -> 31800368   (~127 MB total)
// ---------------------------------------------------------------------------

__device__ __forceinline__ unsigned short f2bf(float f) {
    unsigned u = __float_as_uint(f);
    return (unsigned short)((u + 0x7FFFu + ((u >> 16) & 1u)) >> 16);
}

// Schema GCN + coefficient computation. One block, 512 threads.
__global__ __launch_bounds__(512) void schema_kernel(
    const float* __restrict__ schema_x, const int* __restrict__ sei,
    const float* __restrict__ preW, const float* __restrict__ preb,
    const float* __restrict__ gcnW, const float* __restrict__ gcnb,
    const float* __restrict__ coW, const float* __restrict__ cob,
    float* __restrict__ out_sf, float* __restrict__ out_ori,
    float* __restrict__ coeffs)
{
    __shared__ float h[SS][HDIM];
    __shared__ float xw[SS][HDIM];
    __shared__ float sf[SS][HDIM];
    __shared__ float deg[SS];
    __shared__ float nrm[32];
    __shared__ int es[32], ed[32];

    int t = threadIdx.x;
    int i = t >> 6, j = t & 63;

    float acc = preb[j];
    for (int k = 0; k < INDIM; k++) acc += schema_x[i * INDIM + k] * preW[j * INDIM + k];
    h[i][j] = acc;
    out_ori[i * HDIM + j] = acc;
    if (t < SS) deg[t] = 0.0f;
    __syncthreads();

    if (t < 32) {
        int s, d;
        if (t < 24) { s = sei[t]; d = sei[24 + t]; }
        else        { s = t - 24; d = t - 24; }
        es[t] = s; ed[t] = d;
        atomicAdd(&deg[d], 1.0f);
    }
    __syncthreads();
    if (t < 32) {
        nrm[t] = rsqrtf(fmaxf(deg[es[t]], 1e-12f)) * rsqrtf(fmaxf(deg[ed[t]], 1e-12f));
    }
    float a2 = 0.0f;
    for (int k = 0; k < HDIM; k++) a2 += h[i][k] * gcnW[j * HDIM + k];
    xw[i][j] = a2;
    __syncthreads();

    float o = gcnb[j];
    for (int e = 0; e < 32; e++) {
        if (ed[e] == i) o += xw[es[e]][j] * nrm[e];
    }
    float s = fmaxf(o, 0.0f);
    sf[i][j] = s;
    out_sf[i * HDIM + j] = s;
    __syncthreads();

    if (t < 24) {
        int ty = t >> 3, ii = t & 7;
        int srow = (ty == 1) ? 1 : 0;
        int drow = (ty == 0) ? 1 : 0;
        float a = cob[ii];
        for (int k = 0; k < HDIM; k++) a += sf[srow][k] * coW[ii * (2 * HDIM) + k];
        for (int k = 0; k < HDIM; k++) a += sf[drow][k] * coW[ii * (2 * HDIM) + HDIM + k];
        coeffs[ty * 8 + ii] = a;
    }
}

// W in bf16, row-major [mat][j][k] (B-operand needs contiguous k per row)
__global__ __launch_bounds__(256) void build_w_kernel(
    const float* __restrict__ bases, const float* __restrict__ coeffs,
    unsigned short* __restrict__ Wbf)
{
    int idx = blockIdx.x * blockDim.x + threadIdx.x;   // < 6*16384
    int lt = idx >> 14;
    int jk = idx & 16383;
    int l = lt / 3, ty = lt % 3;
    float acc = 0.0f;
#pragma unroll
    for (int i = 0; i < NBASES; i++)
        acc += coeffs[ty * 8 + i] * bases[((size_t)(l * NBASES + i) << 14) + jk];
    Wbf[idx] = f2bf(acc);
}

__global__ __launch_bounds__(256) void tobf16_kernel(
    const float* __restrict__ in, unsigned short* __restrict__ out, int n)
{
    int i = (blockIdx.x * 256 + threadIdx.x) * 4;
    if (i >= n) return;
    float4 f = *(const float4*)(in + i);
    ushort4 o;
    o.x = f2bf(f.x); o.y = f2bf(f.y); o.z = f2bf(f.z); o.w = f2bf(f.w);
    *(ushort4*)(out + i) = o;
}

__global__ __launch_bounds__(256) void zero_rows_kernel(
    unsigned short* a0, unsigned short* b0, unsigned short* a1, unsigned short* b1)
{
    int t = threadIdx.x;
    int tab = t >> 6, w = t & 63;
    unsigned short* p = (tab == 0) ? a0 : (tab == 1) ? b0 : (tab == 2) ? a1 : b1;
    ((unsigned*)(p + (size_t)NN * CDIM))[w] = 0u;
}

// ---------------- locality-aware CSR build ----------------------------------

__global__ __launch_bounds__(256) void bucket_count_kernel(
    const int* __restrict__ ab, const int* __restrict__ ba,
    const int* __restrict__ aa, int* __restrict__ bcnt)
{
    __shared__ int h[NBUCK];
    int t = threadIdx.x;
    int ty = blockIdx.y;
    const int* ei = (ty == 0) ? ab : (ty == 1) ? ba : aa;
    if (t < NBUCK) h[t] = 0;
    __syncthreads();
    int cb = blockIdx.x * 4096;
    int en = min(cb + 4096, EDGES);
    for (int e = cb + t; e < en; e += 256)
        atomicAdd(&h[ei[EDGES + e] >> BSH], 1);
    __syncthreads();
    if (t < NBUCK) atomicAdd(&bcnt[ty * NBUCK + t], h[t]);
}

__global__ __launch_bounds__(32) void bucket_scan_kernel(
    const int* __restrict__ bcnt, int* __restrict__ boff, int* __restrict__ bcur)
{
    int t = threadIdx.x;
    if (t < 3) {
        int run = 0;
        for (int i = 0; i < NBUCK; i++) {
            int c = bcnt[t * NBUCK + i];
            boff[t * (NBUCK + 1) + i] = run;
            bcur[t * NBUCK + i] = run;
            run += c;
        }
        boff[t * (NBUCK + 1) + NBUCK] = run;
    }
}

__global__ __launch_bounds__(256) void bucket_partition_kernel(
    const int* __restrict__ ab, const int* __restrict__ ba,
    const int* __restrict__ aa, int* __restrict__ bcur,
    unsigned* __restrict__ buf)
{
    __shared__ int h[NBUCK];
    __shared__ int basearr[NBUCK];
    __shared__ int cur[NBUCK];
    int t = threadIdx.x;
    int ty = blockIdx.y;
    const int* ei = (ty == 0) ? ab : (ty == 1) ? ba : aa;
    if (t < NBUCK) h[t] = 0;
    __syncthreads();
    int cb = blockIdx.x * 4096;
    int en = min(cb + 4096, EDGES);
    for (int e = cb + t; e < en; e += 256)
        atomicAdd(&h[ei[EDGES + e] >> BSH], 1);
    __syncthreads();
    if (t < NBUCK) {
        basearr[t] = atomicAdd(&bcur[ty * NBUCK + t], h[t]);
        cur[t] = 0;
    }
    __syncthreads();
    for (int e = cb + t; e < en; e += 256) {
        int src = ei[e], dst = ei[EDGES + e];
        int b = dst >> BSH;
        int r = atomicAdd(&cur[b], 1);
        buf[(size_t)ty * EDGES + basearr[b] + r] =
            ((unsigned)(dst & 511) << 16) | (unsigned)src;
    }
}

// Counting sort within each dst bucket by key (dst&511, src>>CSH): produces
// col[] sorted by (row, src-chunk) and per-(row,chunk) rowptr boundaries.
__global__ __launch_bounds__(256) void bucket_scatter_kernel(
    const unsigned* __restrict__ buf, const int* __restrict__ boff,
    int* __restrict__ rowptr, int* __restrict__ col)
{
    __shared__ int cnt[NKEY];      // 12800 * 4 = 51.2 KB
    __shared__ int part[256];
    int t = threadIdx.x;
    int b = blockIdx.x, ty = blockIdx.y;
    int nstart = boff[ty * (NBUCK + 1) + b];
    int nend   = boff[ty * (NBUCK + 1) + b + 1];
    int n = nend - nstart;
    for (int k = t; k < NKEY; k += 256) cnt[k] = 0;
    __syncthreads();
    const unsigned* bb = buf + (size_t)ty * EDGES + nstart;
    for (int i = t; i < n; i += 256) {
        unsigned pk = bb[i];
        int key = (int)(pk >> 16) * NCHUNK + (int)((pk & 0xFFFFu) >> CSH);
        atomicAdd(&cnt[key], 1);
    }
    __syncthreads();
    // scan: 50 keys per thread (= exactly 2 rows of 25 chunks)
    const int KPT = NKEY / 256;    // 50
    int k0 = t * KPT;
    int lc[KPT];
    int lsum = 0;
#pragma unroll
    for (int j = 0; j < KPT; j++) { lc[j] = cnt[k0 + j]; lsum += lc[j]; }
    part[t] = lsum;
    __syncthreads();
    for (int off2 = 1; off2 < 256; off2 <<= 1) {
        int v = (t >= off2) ? part[t - off2] : 0;
        __syncthreads();
        part[t] += v;
        __syncthreads();
    }
    int run = part[t] - lsum;      // exclusive prefix of this thread's key range
    // write back exclusive prefixes + rowptr entries
    {
        int row_in_b = k0 / NCHUNK;          // = 2t
        int ch = k0 - row_in_b * NCHUNK;     // = 0
        int rowg = (b << BSH) + row_in_b;
        size_t rpbase = (size_t)ty * RPSTR;
#pragma unroll
        for (int j = 0; j < KPT; j++) {
            cnt[k0 + j] = run;
            if (rowg < NN)
                rowptr[rpbase + (size_t)rowg * NCHUNK + ch] = nstart + run;
            run += lc[j];
            ch++;
            if (ch == NCHUNK) { ch = 0; rowg++; }
        }
        if (b == NBUCK - 1 && t == 255)
            rowptr[rpbase + (size_t)NN * NCHUNK] = EDGES;
    }
    __syncthreads();
    int* cc = col + (size_t)ty * EDGES + nstart;
    for (int i = t; i < n; i += 256) {
        unsigned pk = bb[i];
        int key = (int)(pk >> 16) * NCHUNK + (int)((pk & 0xFFFFu) >> CSH);
        int r = atomicAdd(&cnt[key], 1);
        cc[r] = (int)(pk & 0xFFFFu);
    }
}

// ---------------- fused gather + MFMA matmul + LN -> ReLU -------------------

// Chunk-major windowed sweep with batched, branch-free common path:
// per chunk, 8 rows' segments (pad-2: one slot per 32-lane half) issue
// 8 col + 8 uint2 loads back-to-back (MLP ~8); segments >2 edges (P~2.6%)
// go through a fully-unrolled wave-uniform fallback AFTER the batch
// (compile-time rr -> g[] stays in registers; rule #20).
__device__ __forceinline__ void sweep_store(
    const unsigned short* __restrict__ xsrc,
    const int* __restrict__ col, const float* __restrict__ xdst,
    const int* __restrict__ bnd,
    unsigned short* __restrict__ Obf,
    int base, int wv, int half, int off)
{
    float4 g[8];
#pragma unroll
    for (int rr = 0; rr < 8; rr++) g[rr] = make_float4(0.f, 0.f, 0.f, 0.f);

    for (int c = 0; c < NCHUNK; c++) {
        int cs[8];
        unsigned fb = 0;
#pragma unroll
        for (int rr = 0; rr < 8; rr++) {
            int r = rr * 4 + wv;
            int s = bnd[r * NCHUNK + c];
            int e = bnd[r * NCHUNK + c + 1];
            int sl = s + half;
            int cc = col[min(sl, EDGES - 1)];
            cs[rr] = (sl < e) ? cc : NN;
            fb |= (e - s > 2) ? (1u << rr) : 0u;
        }
        uint2 v[8];
#pragma unroll
        for (int rr = 0; rr < 8; rr++)
            v[rr] = *(const uint2*)(xsrc + (size_t)cs[rr] * CDIM + off);
#pragma unroll
        for (int rr = 0; rr < 8; rr++) {
            g[rr].x += __uint_as_float(v[rr].x << 16);
            g[rr].y += __uint_as_float(v[rr].x & 0xffff0000u);
            g[rr].z += __uint_as_float(v[rr].y << 16);
            g[rr].w += __uint_as_float(v[rr].y & 0xffff0000u);
        }
        fb = (unsigned)__builtin_amdgcn_readfirstlane((int)fb);
        if (fb) {
#pragma unroll
            for (int rr = 0; rr < 8; rr++) {     // FULL unroll: rr compile-time,
                if ((fb >> rr) & 1u) {           // g[rr] stays in VGPRs
                    int r = rr * 4 + wv;
                    int s = bnd[r * NCHUNK + c] + 2;
                    int e = bnd[r * NCHUNK + c + 1];
                    for (int b0 = s; b0 < e; b0 += 2) {
                        int sl = b0 + half;
                        int cc = col[min(sl, e - 1)];
                        int id = (sl < e) ? cc : NN;
                        uint2 vv = *(const uint2*)(xsrc + (size_t)id * CDIM + off);
                        g[rr].x += __uint_as_float(vv.x << 16);
                        g[rr].y += __uint_as_float(vv.x & 0xffff0000u);
                        g[rr].z += __uint_as_float(vv.y << 16);
                        g[rr].w += __uint_as_float(vv.y & 0xffff0000u);
                    }
                }
            }
        }
    }

#pragma unroll
    for (int rr = 0; rr < 8; rr++) {
        int r = rr * 4 + wv;
        int row = base + r;
        float4 gg = g[rr];
        gg.x += __shfl_xor(gg.x, 32, 64);
        gg.y += __shfl_xor(gg.y, 32, 64);
        gg.z += __shfl_xor(gg.z, 32, 64);
        gg.w += __shfl_xor(gg.w, 32, 64);
        if (half == 0) {
            ushort4 o = make_ushort4(0, 0, 0, 0);
            if (row < NN) {
                int deg = bnd[r * NCHUNK + NCHUNK] - bnd[r * NCHUNK];
                float inv = 1.0f / (float)max(deg, 1);
                const float4 xv = *(const float4*)(xdst + (size_t)row * CDIM + off);
                o.x = f2bf(gg.x * inv + xv.x);
                o.y = f2bf(gg.y * inv + xv.y);
                o.z = f2bf(gg.z * inv + xv.z);
                o.w = f2bf(gg.w * inv + xv.w);
            }
            *(ushort4*)&Obf[r * USTR + off] = o;
        }
    }
}

// b-side: mean(bf x_a) + x_b -> bf16 U; U @ W^T (MFMA) + bias -> LN -> ReLU
__global__ __launch_bounds__(256, 6) void fuse_b_kernel(
    const unsigned short* __restrict__ xsrc, const float* __restrict__ xdst,
    const int* __restrict__ rowptr, const int* __restrict__ col,
    const unsigned short* __restrict__ Wbf, const float* __restrict__ bias,
    const float* __restrict__ lnw, const float* __restrict__ lnb,
    float* __restrict__ xnext, unsigned short* __restrict__ xnext_bf)
{
    __shared__ float4 smraw[1032];   // max(RROWS*USTR*2, RROWS*SSTR*4) = 16512 B
    __shared__ int bnd[BNDN];
    unsigned short* Ubf = (unsigned short*)smraw;
    float* stage = (float*)smraw;
    int t = threadIdx.x;
    int base = blockIdx.x * RROWS;
    int wv = t >> 6;
    int lane = t & 63;
    int half = lane >> 5, cl = lane & 31;
    int off = cl << 2;

    for (int i = t; i < BNDN; i += 256)
        bnd[i] = rowptr[min(base * NCHUNK + i, NN * NCHUNK)];
    __syncthreads();

    sweep_store(xsrc, col, xdst, bnd, Ubf, base, wv, half, off);
    __syncthreads();

    // MFMA: wave wv -> N-tiles {2wv, 2wv+1}, M-tiles {0,1}
    int qd = lane >> 4;
    int ln16 = lane & 15;
    f32x4 acc00 = {0.f,0.f,0.f,0.f}, acc01 = acc00, acc10 = acc00, acc11 = acc00;
#pragma unroll
    for (int ks = 0; ks < 4; ks++) {
        int koff = ks * 32 + qd * 8;
        bf16x8 a0 = *(const bf16x8*)&Ubf[(ln16) * USTR + koff];
        bf16x8 a1 = *(const bf16x8*)&Ubf[(16 + ln16) * USTR + koff];
        bf16x8 b0 = *(const bf16x8*)&Wbf[(size_t)((2 * wv + 0) * 16 + ln16) * CDIM + koff];
        bf16x8 b1 = *(const bf16x8*)&Wbf[(size_t)((2 * wv + 1) * 16 + ln16) * CDIM + koff];
        acc00 = __builtin_amdgcn_mfma_f32_16x16x32_bf16(a0, b0, acc00, 0, 0, 0);
        acc01 = __builtin_amdgcn_mfma_f32_16x16x32_bf16(a0, b1, acc01, 0, 0, 0);
        acc10 = __builtin_amdgcn_mfma_f32_16x16x32_bf16(a1, b0, acc10, 0, 0, 0);
        acc11 = __builtin_amdgcn_mfma_f32_16x16x32_bf16(a1, b1, acc11, 0, 0, 0);
    }
    __syncthreads();   // all MFMA reads of Ubf done before stage overwrites it
    // C/D layout: col = lane&15 (in tile), row = quad*4 + reg
    {
        int c0 = (2 * wv + 0) * 16 + ln16;
        int c1 = (2 * wv + 1) * 16 + ln16;
#pragma unroll
        for (int i = 0; i < 4; i++) {
            int r0 = qd * 4 + i;
            stage[r0 * SSTR + c0] = acc00[i];
            stage[r0 * SSTR + c1] = acc01[i];
            stage[(16 + r0) * SSTR + c0] = acc10[i];
            stage[(16 + r0) * SSTR + c1] = acc11[i];
        }
    }
    __syncthreads();

    float b0v = bias[lane], b1v = bias[lane + 64];
    float lw0 = lnw[lane], lw1 = lnw[lane + 64];
    float lb0 = lnb[lane], lb1 = lnb[lane + 64];
    for (int rr = 0; rr < RROWS / 4; rr++) {
        int r = rr * 4 + wv;
        int row = base + r;
        if (row >= NN) continue;
        float v0 = stage[r * SSTR + lane] + b0v;
        float v1 = stage[r * SSTR + lane + 64] + b1v;
        float s = v0 + v1, s2 = v0 * v0 + v1 * v1;
#pragma unroll
        for (int o2 = 32; o2 > 0; o2 >>= 1) {
            s  += __shfl_xor(s,  o2, 64);
            s2 += __shfl_xor(s2, o2, 64);
        }
        float mu = s * (1.0f / CDIM);
        float var = s2 * (1.0f / CDIM) - mu * mu;
        float rs = rsqrtf(var + 1e-5f);
        float o0 = fmaxf((v0 - mu) * rs * lw0 + lb0, 0.0f);
        float o1 = fmaxf((v1 - mu) * rs * lw1 + lb1, 0.0f);
        size_t oi = (size_t)row * CDIM;
        xnext[oi + lane] = o0;
        xnext[oi + lane + 64] = o1;
        if (xnext_bf) {
            xnext_bf[oi + lane] = f2bf(o0);
            xnext_bf[oi + lane + 64] = f2bf(o1);
        }
    }
}

// a-side: U = mean_ba(bf x_b)+x_a, V = mean_aa(bf x_a)+x_a;
// out = U@W1^T + V@W2^T + b1 + b2 (MFMA) -> LN -> ReLU
// Two sequential single-table chunk sweeps keep the live window at 512 KB.
__global__ __launch_bounds__(256, 6) void fuse_a_kernel(
    const unsigned short* __restrict__ xsrc1, const int* __restrict__ rowptr1, const int* __restrict__ col1,
    const unsigned short* __restrict__ xsrc2, const int* __restrict__ rowptr2, const int* __restrict__ col2,
    const float* __restrict__ xdst,
    const unsigned short* __restrict__ W1bf, const unsigned short* __restrict__ W2bf,
    const float* __restrict__ bias1, const float* __restrict__ bias2,
    const float* __restrict__ lnw, const float* __restrict__ lnb,
    float* __restrict__ xnext, unsigned short* __restrict__ xnext_bf)
{
    __shared__ float4 smraw[1088];   // max(2*RROWS*USTR*2, RROWS*SSTR*4) = 17408 B
    __shared__ int bnd[BNDN];
    unsigned short* Ubf = (unsigned short*)smraw;
    unsigned short* Vbf = Ubf + RROWS * USTR;
    float* stage = (float*)smraw;
    int t = threadIdx.x;
    int base = blockIdx.x * RROWS;
    int wv = t >> 6;
    int lane = t & 63;
    int half = lane >> 5, cl = lane & 31;
    int off = cl << 2;

    for (int i = t; i < BNDN; i += 256)
        bnd[i] = rowptr1[min(base * NCHUNK + i, NN * NCHUNK)];
    __syncthreads();
    sweep_store(xsrc1, col1, xdst, bnd, Ubf, base, wv, half, off);
    __syncthreads();

    for (int i = t; i < BNDN; i += 256)
        bnd[i] = rowptr2[min(base * NCHUNK + i, NN * NCHUNK)];
    __syncthreads();
    sweep_store(xsrc2, col2, xdst, bnd, Vbf, base, wv, half, off);
    __syncthreads();

    int qd = lane >> 4;
    int ln16 = lane & 15;
    f32x4 acc00 = {0.f,0.f,0.f,0.f}, acc01 = acc00, acc10 = acc00, acc11 = acc00;
#pragma unroll
    for (int ks = 0; ks < 4; ks++) {
        int koff = ks * 32 + qd * 8;
        bf16x8 aU0 = *(const bf16x8*)&Ubf[(ln16) * USTR + koff];
        bf16x8 aU1 = *(const bf16x8*)&Ubf[(16 + ln16) * USTR + koff];
        bf16x8 aV0 = *(const bf16x8*)&Vbf[(ln16) * USTR + koff];
        bf16x8 aV1 = *(const bf16x8*)&Vbf[(16 + ln16) * USTR + koff];
        size_t wrow0 = (size_t)((2 * wv + 0) * 16 + ln16) * CDIM + koff;
        size_t wrow1 = (size_t)((2 * wv + 1) * 16 + ln16) * CDIM + koff;
        bf16x8 b10 = *(const bf16x8*)&W1bf[wrow0];
        bf16x8 b11 = *(const bf16x8*)&W1bf[wrow1];
        bf16x8 b20 = *(const bf16x8*)&W2bf[wrow0];
        bf16x8 b21 = *(const bf16x8*)&W2bf[wrow1];
        acc00 = __builtin_amdgcn_mfma_f32_16x16x32_bf16(aU0, b10, acc00, 0, 0, 0);
        acc01 = __builtin_amdgcn_mfma_f32_16x16x32_bf16(aU0, b11, acc01, 0, 0, 0);
        acc10 = __builtin_amdgcn_mfma_f32_16x16x32_bf16(aU1, b10, acc10, 0, 0, 0);
        acc11 = __builtin_amdgcn_mfma_f32_16x16x32_bf16(aU1, b11, acc11, 0, 0, 0);
        acc00 = __builtin_amdgcn_mfma_f32_16x16x32_bf16(aV0, b20, acc00, 0, 0, 0);
        acc01 = __builtin_amdgcn_mfma_f32_16x16x32_bf16(aV0, b21, acc01, 0, 0, 0);
        acc10 = __builtin_amdgcn_mfma_f32_16x16x32_bf16(aV1, b20, acc10, 0, 0, 0);
        acc11 = __builtin_amdgcn_mfma_f32_16x16x32_bf16(aV1, b21, acc11, 0, 0, 0);
    }
    __syncthreads();   // all MFMA reads of Ubf/Vbf done before stage overwrites them
    {
        int c0 = (2 * wv + 0) * 16 + ln16;
        int c1 = (2 * wv + 1) * 16 + ln16;
#pragma unroll
        for (int i = 0; i < 4; i++) {
            int r0 = qd * 4 + i;
            stage[r0 * SSTR + c0] = acc00[i];
            stage[r0 * SSTR + c1] = acc01[i];
            stage[(16 + r0) * SSTR + c0] = acc10[i];
            stage[(16 + r0) * SSTR + c1] = acc11[i];
        }
    }
    __syncthreads();

    float b0v = bias1[lane] + bias2[lane];
    float b1v = bias1[lane + 64] + bias2[lane + 64];
    float lw0 = lnw[lane], lw1 = lnw[lane + 64];
    float lb0 = lnb[lane], lb1 = lnb[lane + 64];
    for (int rr = 0; rr < RROWS / 4; rr++) {
        int r = rr * 4 + wv;
        int row = base + r;
        if (row >= NN) continue;
        float v0 = stage[r * SSTR + lane] + b0v;
        float v1 = stage[r * SSTR + lane + 64] + b1v;
        float s = v0 + v1, s2 = v0 * v0 + v1 * v1;
#pragma unroll
        for (int o2 = 32; o2 > 0; o2 >>= 1) {
            s  += __shfl_xor(s,  o2, 64);
            s2 += __shfl_xor(s2, o2, 64);
        }
        float mu = s * (1.0f / CDIM);
        float var = s2 * (1.0f / CDIM) - mu * mu;
        float rs = rsqrtf(var + 1e-5f);
        float o0 = fmaxf((v0 - mu) * rs * lw0 + lb0, 0.0f);
        float o1 = fmaxf((v1 - mu) * rs * lw1 + lb1, 0.0f);
        size_t oi = (size_t)row * CDIM;
        xnext[oi + lane] = o0;
        xnext[oi + lane + 64] = o1;
        if (xnext_bf) {
            xnext_bf[oi + lane] = f2bf(o0);
            xnext_bf[oi + lane + 64] = f2bf(o1);
        }
    }
}

extern "C" void kernel_launch(void* const* d_in, const int* in_sizes, int n_in,
                              void* d_out, int out_size, void* d_ws, size_t ws_size,
                              hipStream_t stream)
{
    const float* x_a      = (const float*)d_in[0];
    const float* x_b      = (const float*)d_in[1];
    const float* schema_x = (const float*)d_in[2];
    const int*   e_ab     = (const int*)d_in[3];
    const int*   e_ba     = (const int*)d_in[4];
    const int*   e_aa     = (const int*)d_in[5];
    const int*   sei      = (const int*)d_in[6];
    const float* preW     = (const float*)d_in[7];
    const float* preb     = (const float*)d_in[8];
    const float* gcnW     = (const float*)d_in[9];
    const float* gcnb     = (const float*)d_in[10];
    const float* coW      = (const float*)d_in[11];
    const float* cob      = (const float*)d_in[12];
    const float* bases    = (const float*)d_in[13];
    const float* sbias    = (const float*)d_in[14];
    const float* lnw      = (const float*)d_in[15];
    const float* lnb      = (const float*)d_in[16];

    float* out     = (float*)d_out;
    float* out_xa  = out;
    float* out_xb  = out + 6400000;
    float* out_sf  = out + 12800000;
    float* out_ori = out + 12800512;

    float* ws = (float*)d_ws;
    int*      col    = (int*)ws;
    int*      rowptr = (int*)(ws + 2400000);
    int*      bcnt   = (int*)(ws + 6150016);
    int*      boff   = (int*)(ws + 6150320);
    int*      bcur   = (int*)(ws + 6150624);
    float* xa_buf = ws + 6150928;
    unsigned* buf = (unsigned*)xa_buf;     // aliases xa_buf head; dead before layer-0 fuse_a
    float* xb_buf = ws + 12550928;
    unsigned short* Wbf = (unsigned short*)(ws + 18950928);
    float* coeffs = ws + 19000080;
    unsigned short* xa_bf0 = (unsigned short*)(ws + 19000112);
    unsigned short* xb_bf0 = (unsigned short*)(ws + 22200176);
    unsigned short* xa_bf1 = (unsigned short*)(ws + 25400240);
    unsigned short* xb_bf1 = (unsigned short*)(ws + 28600304);

    schema_kernel<<<1, 512, 0, stream>>>(schema_x, sei, preW, preb, gcnW, gcnb,
                                         coW, cob, out_sf, out_ori, coeffs);
    build_w_kernel<<<384, 256, 0, stream>>>(bases, coeffs, Wbf);

    tobf16_kernel<<<(NA * CDIM / 4 + 255) / 256, 256, 0, stream>>>(x_a, xa_bf0, NA * CDIM);
    tobf16_kernel<<<(NB * CDIM / 4 + 255) / 256, 256, 0, stream>>>(x_b, xb_bf0, NB * CDIM);
    zero_rows_kernel<<<1, 256, 0, stream>>>(xa_bf0, xb_bf0, xa_bf1, xb_bf1);

    hipMemsetAsync(bcnt, 0, 3 * NBUCK * sizeof(int), stream);
    dim3 cgrid((EDGES + 4095) / 4096, 3);
    bucket_count_kernel<<<cgrid, 256, 0, stream>>>(e_ab, e_ba, e_aa, bcnt);
    bucket_scan_kernel<<<1, 32, 0, stream>>>(bcnt, boff, bcur);
    bucket_partition_kernel<<<cgrid, 256, 0, stream>>>(e_ab, e_ba, e_aa, bcur, buf);
    dim3 sgrid(NBUCK, 3);
    bucket_scatter_kernel<<<sgrid, 256, 0, stream>>>(buf, boff, rowptr, col);

    const int* rp_ab = rowptr;
    const int* rp_ba = rowptr + RPSTR;
    const int* rp_aa = rowptr + 2 * RPSTR;
    const int* col_ab = col;
    const int* col_ba = col + EDGES;
    const int* col_aa = col + 2 * EDGES;

    const int fgrid = (NN + RROWS - 1) / RROWS;   // 1563

    for (int l = 0; l < 2; l++) {
        const float* xa_cur = (l == 0) ? x_a : xa_buf;
        const float* xb_cur = (l == 0) ? x_b : xb_buf;
        const unsigned short* xa_bf = (l == 0) ? xa_bf0 : xa_bf1;
        const unsigned short* xb_bf = (l == 0) ? xb_bf0 : xb_bf1;
        const unsigned short* Wab = Wbf + (size_t)(l * 3 + 0) * 16384;
        const unsigned short* Wba = Wbf + (size_t)(l * 3 + 1) * 16384;
        const unsigned short* Waa = Wbf + (size_t)(l * 3 + 2) * 16384;
        float* xa_nxt = (l == 0) ? xa_buf : out_xa;
        float* xb_nxt = (l == 0) ? xb_buf : out_xb;
        unsigned short* xa_nbf = (l == 0) ? xa_bf1 : nullptr;
        unsigned short* xb_nbf = (l == 0) ? xb_bf1 : nullptr;

        fuse_b_kernel<<<fgrid, 256, 0, stream>>>(
            xa_bf, xb_cur, rp_ab, col_ab, Wab,
            sbias + (size_t)(l * 3 + 0) * 128,
            lnw + (size_t)(l * 2 + 1) * 128, lnb + (size_t)(l * 2 + 1) * 128,
            xb_nxt, xb_nbf);
        fuse_a_kernel<<<fgrid, 256, 0, stream>>>(
            xb_bf, rp_ba, col_ba, xa_bf, rp_aa, col_aa, xa_cur,
            Wba, Waa,
            sbias + (size_t)(l * 3 + 1) * 128, sbias + (size_t)(l * 3 + 2) * 128,
            lnw + (size_t)(l * 2 + 0) * 128, lnb + (size_t)(l * 2 + 0) * 128,
            xa_nxt, xa_nbf);
    }
}

// Round 7
// 589.485 us; speedup vs baseline: 4.6076x; 2.1953x over previous
//
#include <hip/hip_runtime.h>

#define NA 50000
#define NB 50000
#define NN 50000
#define CDIM 128
#define EDGES 800000
#define SS 8
#define INDIM 64
#define HDIM 64
#define NBASES 8
#define NBUCK 98
#define BSH 9
#define NCHUNK 7           // src chunks of 8192 rows (2 MB bf16) for L2-windowed gather
#define CSH 13
#define NKEY (512 * NCHUNK)   // 3584 counting-sort keys per dst bucket
#define RPSTR (NN * NCHUNK + 1)
#define BNDN (32 * NCHUNK + 1)   // 225 per-block boundary entries

#define RROWS 32
#define USTR 136   // ushort stride (pad) for bf16 U/V tiles
#define SSTR 129   // float stride for acc staging

typedef __attribute__((ext_vector_type(8))) short bf16x8;
typedef __attribute__((ext_vector_type(4))) float f32x4;

// ---------------------------------------------------------------------------
// Workspace layout (4-byte element offsets) — audited:
//   0         col      [3*E]              int    -> 2400000
//   2400000   rowptr   [3*(NN*7+1)]       int    -> 3450003
//   6150016   bcnt / 6150320 boff / 6150624 bcur
//   6150928   xa_buf   [NA*128] float  -> 12550928   (buf aliases head; dead
//                                                     before layer-0 fuse_a)
//   12550928  xb_buf   -> 18950928
//   18950928  Wbf      ushort[98304] = 49152 words -> 19000080
//   19000080  coeffs   [24] float (pad to 19000112)
//   19000112  xa_bf0   ushort[(NN+1)*128] = 3200064 words -> 22200176
//   22200176  xb_bf0   -> 25400240
//   25400240  xa_bf1   -> 28600304
//   28600304  xb_bf1   -> 31800368   (~127 MB total)
// ---------------------------------------------------------------------------

__device__ __forceinline__ unsigned short f2bf(float f) {
    unsigned u = __float_as_uint(f);
    return (unsigned short)((u + 0x7FFFu + ((u >> 16) & 1u)) >> 16);
}

// Schema GCN + coefficient computation. One block, 512 threads.
__global__ __launch_bounds__(512) void schema_kernel(
    const float* __restrict__ schema_x, const int* __restrict__ sei,
    const float* __restrict__ preW, const float* __restrict__ preb,
    const float* __restrict__ gcnW, const float* __restrict__ gcnb,
    const float* __restrict__ coW, const float* __restrict__ cob,
    float* __restrict__ out_sf, float* __restrict__ out_ori,
    float* __restrict__ coeffs)
{
    __shared__ float h[SS][HDIM];
    __shared__ float xw[SS][HDIM];
    __shared__ float sf[SS][HDIM];
    __shared__ float deg[SS];
    __shared__ float nrm[32];
    __shared__ int es[32], ed[32];

    int t = threadIdx.x;
    int i = t >> 6, j = t & 63;

    float acc = preb[j];
    for (int k = 0; k < INDIM; k++) acc += schema_x[i * INDIM + k] * preW[j * INDIM + k];
    h[i][j] = acc;
    out_ori[i * HDIM + j] = acc;
    if (t < SS) deg[t] = 0.0f;
    __syncthreads();

    if (t < 32) {
        int s, d;
        if (t < 24) { s = sei[t]; d = sei[24 + t]; }
        else        { s = t - 24; d = t - 24; }
        es[t] = s; ed[t] = d;
        atomicAdd(&deg[d], 1.0f);
    }
    __syncthreads();
    if (t < 32) {
        nrm[t] = rsqrtf(fmaxf(deg[es[t]], 1e-12f)) * rsqrtf(fmaxf(deg[ed[t]], 1e-12f));
    }
    float a2 = 0.0f;
    for (int k = 0; k < HDIM; k++) a2 += h[i][k] * gcnW[j * HDIM + k];
    xw[i][j] = a2;
    __syncthreads();

    float o = gcnb[j];
    for (int e = 0; e < 32; e++) {
        if (ed[e] == i) o += xw[es[e]][j] * nrm[e];
    }
    float s = fmaxf(o, 0.0f);
    sf[i][j] = s;
    out_sf[i * HDIM + j] = s;
    __syncthreads();

    if (t < 24) {
        int ty = t >> 3, ii = t & 7;
        int srow = (ty == 1) ? 1 : 0;
        int drow = (ty == 0) ? 1 : 0;
        float a = cob[ii];
        for (int k = 0; k < HDIM; k++) a += sf[srow][k] * coW[ii * (2 * HDIM) + k];
        for (int k = 0; k < HDIM; k++) a += sf[drow][k] * coW[ii * (2 * HDIM) + HDIM + k];
        coeffs[ty * 8 + ii] = a;
    }
}

// W in bf16, row-major [mat][j][k] (B-operand needs contiguous k per row)
__global__ __launch_bounds__(256) void build_w_kernel(
    const float* __restrict__ bases, const float* __restrict__ coeffs,
    unsigned short* __restrict__ Wbf)
{
    int idx = blockIdx.x * blockDim.x + threadIdx.x;   // < 6*16384
    int lt = idx >> 14;
    int jk = idx & 16383;
    int l = lt / 3, ty = lt % 3;
    float acc = 0.0f;
#pragma unroll
    for (int i = 0; i < NBASES; i++)
        acc += coeffs[ty * 8 + i] * bases[((size_t)(l * NBASES + i) << 14) + jk];
    Wbf[idx] = f2bf(acc);
}

__global__ __launch_bounds__(256) void tobf16_kernel(
    const float* __restrict__ in, unsigned short* __restrict__ out, int n)
{
    int i = (blockIdx.x * 256 + threadIdx.x) * 4;
    if (i >= n) return;
    float4 f = *(const float4*)(in + i);
    ushort4 o;
    o.x = f2bf(f.x); o.y = f2bf(f.y); o.z = f2bf(f.z); o.w = f2bf(f.w);
    *(ushort4*)(out + i) = o;
}

__global__ __launch_bounds__(256) void zero_rows_kernel(
    unsigned short* a0, unsigned short* b0, unsigned short* a1, unsigned short* b1)
{
    int t = threadIdx.x;
    int tab = t >> 6, w = t & 63;
    unsigned short* p = (tab == 0) ? a0 : (tab == 1) ? b0 : (tab == 2) ? a1 : b1;
    ((unsigned*)(p + (size_t)NN * CDIM))[w] = 0u;
}

// ---------------- locality-aware CSR build ----------------------------------

__global__ __launch_bounds__(256) void bucket_count_kernel(
    const int* __restrict__ ab, const int* __restrict__ ba,
    const int* __restrict__ aa, int* __restrict__ bcnt)
{
    __shared__ int h[NBUCK];
    int t = threadIdx.x;
    int ty = blockIdx.y;
    const int* ei = (ty == 0) ? ab : (ty == 1) ? ba : aa;
    if (t < NBUCK) h[t] = 0;
    __syncthreads();
    int cb = blockIdx.x * 4096;
    int en = min(cb + 4096, EDGES);
    for (int e = cb + t; e < en; e += 256)
        atomicAdd(&h[ei[EDGES + e] >> BSH], 1);
    __syncthreads();
    if (t < NBUCK) atomicAdd(&bcnt[ty * NBUCK + t], h[t]);
}

__global__ __launch_bounds__(32) void bucket_scan_kernel(
    const int* __restrict__ bcnt, int* __restrict__ boff, int* __restrict__ bcur)
{
    int t = threadIdx.x;
    if (t < 3) {
        int run = 0;
        for (int i = 0; i < NBUCK; i++) {
            int c = bcnt[t * NBUCK + i];
            boff[t * (NBUCK + 1) + i] = run;
            bcur[t * NBUCK + i] = run;
            run += c;
        }
        boff[t * (NBUCK + 1) + NBUCK] = run;
    }
}

__global__ __launch_bounds__(256) void bucket_partition_kernel(
    const int* __restrict__ ab, const int* __restrict__ ba,
    const int* __restrict__ aa, int* __restrict__ bcur,
    unsigned* __restrict__ buf)
{
    __shared__ int h[NBUCK];
    __shared__ int basearr[NBUCK];
    __shared__ int cur[NBUCK];
    int t = threadIdx.x;
    int ty = blockIdx.y;
    const int* ei = (ty == 0) ? ab : (ty == 1) ? ba : aa;
    if (t < NBUCK) h[t] = 0;
    __syncthreads();
    int cb = blockIdx.x * 4096;
    int en = min(cb + 4096, EDGES);
    for (int e = cb + t; e < en; e += 256)
        atomicAdd(&h[ei[EDGES + e] >> BSH], 1);
    __syncthreads();
    if (t < NBUCK) {
        basearr[t] = atomicAdd(&bcur[ty * NBUCK + t], h[t]);
        cur[t] = 0;
    }
    __syncthreads();
    for (int e = cb + t; e < en; e += 256) {
        int src = ei[e], dst = ei[EDGES + e];
        int b = dst >> BSH;
        int r = atomicAdd(&cur[b], 1);
        buf[(size_t)ty * EDGES + basearr[b] + r] =
            ((unsigned)(dst & 511) << 16) | (unsigned)src;
    }
}

// Counting sort within each dst bucket by key (dst&511, src>>CSH): produces
// col[] sorted by (row, src-chunk) and per-(row,chunk) rowptr boundaries.
__global__ __launch_bounds__(256) void bucket_scatter_kernel(
    const unsigned* __restrict__ buf, const int* __restrict__ boff,
    int* __restrict__ rowptr, int* __restrict__ col)
{
    __shared__ int cnt[NKEY];      // 3584 * 4 = 14.3 KB
    __shared__ int part[256];
    int t = threadIdx.x;
    int b = blockIdx.x, ty = blockIdx.y;
    int nstart = boff[ty * (NBUCK + 1) + b];
    int nend   = boff[ty * (NBUCK + 1) + b + 1];
    int n = nend - nstart;
    for (int k = t; k < NKEY; k += 256) cnt[k] = 0;
    __syncthreads();
    const unsigned* bb = buf + (size_t)ty * EDGES + nstart;
    for (int i = t; i < n; i += 256) {
        unsigned pk = bb[i];
        int key = (int)(pk >> 16) * NCHUNK + (int)((pk & 0xFFFFu) >> CSH);
        atomicAdd(&cnt[key], 1);
    }
    __syncthreads();
    // scan: 14 keys per thread (= exactly 2 rows of 7 chunks)
    const int KPT = NKEY / 256;    // 14
    int k0 = t * KPT;
    int lc[KPT];
    int lsum = 0;
#pragma unroll
    for (int j = 0; j < KPT; j++) { lc[j] = cnt[k0 + j]; lsum += lc[j]; }
    part[t] = lsum;
    __syncthreads();
    for (int off2 = 1; off2 < 256; off2 <<= 1) {
        int v = (t >= off2) ? part[t - off2] : 0;
        __syncthreads();
        part[t] += v;
        __syncthreads();
    }
    int run = part[t] - lsum;      // exclusive prefix of this thread's key range
    // write back exclusive prefixes + rowptr entries
    {
        int row_in_b = k0 / NCHUNK;          // = 2t
        int ch = k0 - row_in_b * NCHUNK;     // = 0
        int rowg = (b << BSH) + row_in_b;
        size_t rpbase = (size_t)ty * RPSTR;
#pragma unroll
        for (int j = 0; j < KPT; j++) {
            cnt[k0 + j] = run;
            if (rowg < NN)
                rowptr[rpbase + (size_t)rowg * NCHUNK + ch] = nstart + run;
            run += lc[j];
            ch++;
            if (ch == NCHUNK) { ch = 0; rowg++; }
        }
        if (b == NBUCK - 1 && t == 255)
            rowptr[rpbase + (size_t)NN * NCHUNK] = EDGES;
    }
    __syncthreads();
    int* cc = col + (size_t)ty * EDGES + nstart;
    for (int i = t; i < n; i += 256) {
        unsigned pk = bb[i];
        int key = (int)(pk >> 16) * NCHUNK + (int)((pk & 0xFFFFu) >> CSH);
        int r = atomicAdd(&cnt[key], 1);
        cc[r] = (int)(pk & 0xFFFFu);
    }
}

// ---------------- fused gather + MFMA matmul + LN -> ReLU -------------------

// Chunk-major windowed sweep (2 MB src windows -> L2-resident gathers) with a
// batched branch-free common path: per chunk, each row issues 4 slots (2 per
// 32-lane half) -> 16 independent col + 16 independent uint2 loads per thread
// batch (MLP high). Segments >4 edges (P~9%, Poisson(2.3)) go through a
// fully-unrolled wave-uniform fallback AFTER the batch (compile-time rr ->
// g[] stays in registers; rule #20). Empty/pad slots read the zero row
// (L1-resident). Boundaries come from LDS (bnd), staged once per CSR.
__device__ __forceinline__ void sweep_store(
    const unsigned short* __restrict__ xsrc,
    const int* __restrict__ col, const float* __restrict__ xdst,
    const int* __restrict__ bnd,
    unsigned short* __restrict__ Obf,
    int base, int wv, int half, int off)
{
    float4 g[8];
#pragma unroll
    for (int rr = 0; rr < 8; rr++) g[rr] = make_float4(0.f, 0.f, 0.f, 0.f);

    for (int c = 0; c < NCHUNK; c++) {
        int cs0[8], cs1[8];
        unsigned fb = 0;
#pragma unroll
        for (int rr = 0; rr < 8; rr++) {
            int r = rr * 4 + wv;
            int s = bnd[r * NCHUNK + c];
            int e = bnd[r * NCHUNK + c + 1];
            int sl0 = s + half;
            int sl1 = s + 2 + half;
            int c0 = col[min(sl0, EDGES - 1)];
            int c1 = col[min(sl1, EDGES - 1)];
            cs0[rr] = (sl0 < e) ? c0 : NN;
            cs1[rr] = (sl1 < e) ? c1 : NN;
            fb |= (e - s > 4) ? (1u << rr) : 0u;
        }
        uint2 v0[8], v1[8];
#pragma unroll
        for (int rr = 0; rr < 8; rr++) {
            v0[rr] = *(const uint2*)(xsrc + (size_t)cs0[rr] * CDIM + off);
            v1[rr] = *(const uint2*)(xsrc + (size_t)cs1[rr] * CDIM + off);
        }
#pragma unroll
        for (int rr = 0; rr < 8; rr++) {
            g[rr].x += __uint_as_float(v0[rr].x << 16) + __uint_as_float(v1[rr].x << 16);
            g[rr].y += __uint_as_float(v0[rr].x & 0xffff0000u) + __uint_as_float(v1[rr].x & 0xffff0000u);
            g[rr].z += __uint_as_float(v0[rr].y << 16) + __uint_as_float(v1[rr].y << 16);
            g[rr].w += __uint_as_float(v0[rr].y & 0xffff0000u) + __uint_as_float(v1[rr].y & 0xffff0000u);
        }
        fb = (unsigned)__builtin_amdgcn_readfirstlane((int)fb);
        if (fb) {
#pragma unroll
            for (int rr = 0; rr < 8; rr++) {     // FULL unroll: rr compile-time,
                if ((fb >> rr) & 1u) {           // g[rr] stays in VGPRs
                    int r = rr * 4 + wv;
                    int s = bnd[r * NCHUNK + c] + 4;
                    int e = bnd[r * NCHUNK + c + 1];
                    for (int b0 = s; b0 < e; b0 += 4) {
                        int sl0 = b0 + half;
                        int sl1 = b0 + 2 + half;
                        int c0 = col[min(sl0, e - 1)];
                        int c1 = col[min(sl1, e - 1)];
                        int i0 = (sl0 < e) ? c0 : NN;
                        int i1 = (sl1 < e) ? c1 : NN;
                        uint2 w0 = *(const uint2*)(xsrc + (size_t)i0 * CDIM + off);
                        uint2 w1 = *(const uint2*)(xsrc + (size_t)i1 * CDIM + off);
                        g[rr].x += __uint_as_float(w0.x << 16) + __uint_as_float(w1.x << 16);
                        g[rr].y += __uint_as_float(w0.x & 0xffff0000u) + __uint_as_float(w1.x & 0xffff0000u);
                        g[rr].z += __uint_as_float(w0.y << 16) + __uint_as_float(w1.y << 16);
                        g[rr].w += __uint_as_float(w0.y & 0xffff0000u) + __uint_as_float(w1.y & 0xffff0000u);
                    }
                }
            }
        }
    }

#pragma unroll
    for (int rr = 0; rr < 8; rr++) {
        int r = rr * 4 + wv;
        int row = base + r;
        float4 gg = g[rr];
        gg.x += __shfl_xor(gg.x, 32, 64);
        gg.y += __shfl_xor(gg.y, 32, 64);
        gg.z += __shfl_xor(gg.z, 32, 64);
        gg.w += __shfl_xor(gg.w, 32, 64);
        if (half == 0) {
            ushort4 o = make_ushort4(0, 0, 0, 0);
            if (row < NN) {
                int deg = bnd[r * NCHUNK + NCHUNK] - bnd[r * NCHUNK];
                float inv = 1.0f / (float)max(deg, 1);
                const float4 xv = *(const float4*)(xdst + (size_t)row * CDIM + off);
                o.x = f2bf(gg.x * inv + xv.x);
                o.y = f2bf(gg.y * inv + xv.y);
                o.z = f2bf(gg.z * inv + xv.z);
                o.w = f2bf(gg.w * inv + xv.w);
            }
            *(ushort4*)&Obf[r * USTR + off] = o;
        }
    }
}

// b-side: mean(bf x_a) + x_b -> bf16 U; U @ W^T (MFMA) + bias -> LN -> ReLU
__global__ __launch_bounds__(256, 4) void fuse_b_kernel(
    const unsigned short* __restrict__ xsrc, const float* __restrict__ xdst,
    const int* __restrict__ rowptr, const int* __restrict__ col,
    const unsigned short* __restrict__ Wbf, const float* __restrict__ bias,
    const float* __restrict__ lnw, const float* __restrict__ lnb,
    float* __restrict__ xnext, unsigned short* __restrict__ xnext_bf)
{
    __shared__ float4 smraw[1032];   // max(RROWS*USTR*2, RROWS*SSTR*4) = 16512 B
    __shared__ int bnd[BNDN];
    unsigned short* Ubf = (unsigned short*)smraw;
    float* stage = (float*)smraw;
    int t = threadIdx.x;
    int base = blockIdx.x * RROWS;
    int wv = t >> 6;
    int lane = t & 63;
    int half = lane >> 5, cl = lane & 31;
    int off = cl << 2;

    for (int i = t; i < BNDN; i += 256)
        bnd[i] = rowptr[min(base * NCHUNK + i, NN * NCHUNK)];
    __syncthreads();

    sweep_store(xsrc, col, xdst, bnd, Ubf, base, wv, half, off);
    __syncthreads();

    // MFMA: wave wv -> N-tiles {2wv, 2wv+1}, M-tiles {0,1}
    int qd = lane >> 4;
    int ln16 = lane & 15;
    f32x4 acc00 = {0.f,0.f,0.f,0.f}, acc01 = acc00, acc10 = acc00, acc11 = acc00;
#pragma unroll
    for (int ks = 0; ks < 4; ks++) {
        int koff = ks * 32 + qd * 8;
        bf16x8 a0 = *(const bf16x8*)&Ubf[(ln16) * USTR + koff];
        bf16x8 a1 = *(const bf16x8*)&Ubf[(16 + ln16) * USTR + koff];
        bf16x8 b0 = *(const bf16x8*)&Wbf[(size_t)((2 * wv + 0) * 16 + ln16) * CDIM + koff];
        bf16x8 b1 = *(const bf16x8*)&Wbf[(size_t)((2 * wv + 1) * 16 + ln16) * CDIM + koff];
        acc00 = __builtin_amdgcn_mfma_f32_16x16x32_bf16(a0, b0, acc00, 0, 0, 0);
        acc01 = __builtin_amdgcn_mfma_f32_16x16x32_bf16(a0, b1, acc01, 0, 0, 0);
        acc10 = __builtin_amdgcn_mfma_f32_16x16x32_bf16(a1, b0, acc10, 0, 0, 0);
        acc11 = __builtin_amdgcn_mfma_f32_16x16x32_bf16(a1, b1, acc11, 0, 0, 0);
    }
    __syncthreads();   // all MFMA reads of Ubf done before stage overwrites it
    // C/D layout: col = lane&15 (in tile), row = quad*4 + reg
    {
        int c0 = (2 * wv + 0) * 16 + ln16;
        int c1 = (2 * wv + 1) * 16 + ln16;
#pragma unroll
        for (int i = 0; i < 4; i++) {
            int r0 = qd * 4 + i;
            stage[r0 * SSTR + c0] = acc00[i];
            stage[r0 * SSTR + c1] = acc01[i];
            stage[(16 + r0) * SSTR + c0] = acc10[i];
            stage[(16 + r0) * SSTR + c1] = acc11[i];
        }
    }
    __syncthreads();

    float b0v = bias[lane], b1v = bias[lane + 64];
    float lw0 = lnw[lane], lw1 = lnw[lane + 64];
    float lb0 = lnb[lane], lb1 = lnb[lane + 64];
    for (int rr = 0; rr < RROWS / 4; rr++) {
        int r = rr * 4 + wv;
        int row = base + r;
        if (row >= NN) continue;
        float v0 = stage[r * SSTR + lane] + b0v;
        float v1 = stage[r * SSTR + lane + 64] + b1v;
        float s = v0 + v1, s2 = v0 * v0 + v1 * v1;
#pragma unroll
        for (int o2 = 32; o2 > 0; o2 >>= 1) {
            s  += __shfl_xor(s,  o2, 64);
            s2 += __shfl_xor(s2, o2, 64);
        }
        float mu = s * (1.0f / CDIM);
        float var = s2 * (1.0f / CDIM) - mu * mu;
        float rs = rsqrtf(var + 1e-5f);
        float o0 = fmaxf((v0 - mu) * rs * lw0 + lb0, 0.0f);
        float o1 = fmaxf((v1 - mu) * rs * lw1 + lb1, 0.0f);
        size_t oi = (size_t)row * CDIM;
        xnext[oi + lane] = o0;
        xnext[oi + lane + 64] = o1;
        if (xnext_bf) {
            xnext_bf[oi + lane] = f2bf(o0);
            xnext_bf[oi + lane + 64] = f2bf(o1);
        }
    }
}

// a-side: U = mean_ba(bf x_b)+x_a, V = mean_aa(bf x_a)+x_a;
// out = U@W1^T + V@W2^T + b1 + b2 (MFMA) -> LN -> ReLU
// Two sequential single-table chunk sweeps keep the live window at 2 MB.
__global__ __launch_bounds__(256, 4) void fuse_a_kernel(
    const unsigned short* __restrict__ xsrc1, const int* __restrict__ rowptr1, const int* __restrict__ col1,
    const unsigned short* __restrict__ xsrc2, const int* __restrict__ rowptr2, const int* __restrict__ col2,
    const float* __restrict__ xdst,
    const unsigned short* __restrict__ W1bf, const unsigned short* __restrict__ W2bf,
    const float* __restrict__ bias1, const float* __restrict__ bias2,
    const float* __restrict__ lnw, const float* __restrict__ lnb,
    float* __restrict__ xnext, unsigned short* __restrict__ xnext_bf)
{
    __shared__ float4 smraw[1088];   // max(2*RROWS*USTR*2, RROWS*SSTR*4) = 17408 B
    __shared__ int bnd[BNDN];
    unsigned short* Ubf = (unsigned short*)smraw;
    unsigned short* Vbf = Ubf + RROWS * USTR;
    float* stage = (float*)smraw;
    int t = threadIdx.x;
    int base = blockIdx.x * RROWS;
    int wv = t >> 6;
    int lane = t & 63;
    int half = lane >> 5, cl = lane & 31;
    int off = cl << 2;

    for (int i = t; i < BNDN; i += 256)
        bnd[i] = rowptr1[min(base * NCHUNK + i, NN * NCHUNK)];
    __syncthreads();
    sweep_store(xsrc1, col1, xdst, bnd, Ubf, base, wv, half, off);
    __syncthreads();

    for (int i = t; i < BNDN; i += 256)
        bnd[i] = rowptr2[min(base * NCHUNK + i, NN * NCHUNK)];
    __syncthreads();
    sweep_store(xsrc2, col2, xdst, bnd, Vbf, base, wv, half, off);
    __syncthreads();

    int qd = lane >> 4;
    int ln16 = lane & 15;
    f32x4 acc00 = {0.f,0.f,0.f,0.f}, acc01 = acc00, acc10 = acc00, acc11 = acc00;
#pragma unroll
    for (int ks = 0; ks < 4; ks++) {
        int koff = ks * 32 + qd * 8;
        bf16x8 aU0 = *(const bf16x8*)&Ubf[(ln16) * USTR + koff];
        bf16x8 aU1 = *(const bf16x8*)&Ubf[(16 + ln16) * USTR + koff];
        bf16x8 aV0 = *(const bf16x8*)&Vbf[(ln16) * USTR + koff];
        bf16x8 aV1 = *(const bf16x8*)&Vbf[(16 + ln16) * USTR + koff];
        size_t wrow0 = (size_t)((2 * wv + 0) * 16 + ln16) * CDIM + koff;
        size_t wrow1 = (size_t)((2 * wv + 1) * 16 + ln16) * CDIM + koff;
        bf16x8 b10 = *(const bf16x8*)&W1bf[wrow0];
        bf16x8 b11 = *(const bf16x8*)&W1bf[wrow1];
        bf16x8 b20 = *(const bf16x8*)&W2bf[wrow0];
        bf16x8 b21 = *(const bf16x8*)&W2bf[wrow1];
        acc00 = __builtin_amdgcn_mfma_f32_16x16x32_bf16(aU0, b10, acc00, 0, 0, 0);
        acc01 = __builtin_amdgcn_mfma_f32_16x16x32_bf16(aU0, b11, acc01, 0, 0, 0);
        acc10 = __builtin_amdgcn_mfma_f32_16x16x32_bf16(aU1, b10, acc10, 0, 0, 0);
        acc11 = __builtin_amdgcn_mfma_f32_16x16x32_bf16(aU1, b11, acc11, 0, 0, 0);
        acc00 = __builtin_amdgcn_mfma_f32_16x16x32_bf16(aV0, b20, acc00, 0, 0, 0);
        acc01 = __builtin_amdgcn_mfma_f32_16x16x32_bf16(aV0, b21, acc01, 0, 0, 0);
        acc10 = __builtin_amdgcn_mfma_f32_16x16x32_bf16(aV1, b20, acc10, 0, 0, 0);
        acc11 = __builtin_amdgcn_mfma_f32_16x16x32_bf16(aV1, b21, acc11, 0, 0, 0);
    }
    __syncthreads();   // all MFMA reads of Ubf/Vbf done before stage overwrites them
    {
        int c0 = (2 * wv + 0) * 16 + ln16;
        int c1 = (2 * wv + 1) * 16 + ln16;
#pragma unroll
        for (int i = 0; i < 4; i++) {
            int r0 = qd * 4 + i;
            stage[r0 * SSTR + c0] = acc00[i];
            stage[r0 * SSTR + c1] = acc01[i];
            stage[(16 + r0) * SSTR + c0] = acc10[i];
            stage[(16 + r0) * SSTR + c1] = acc11[i];
        }
    }
    __syncthreads();

    float b0v = bias1[lane] + bias2[lane];
    float b1v = bias1[lane + 64] + bias2[lane + 64];
    float lw0 = lnw[lane], lw1 = lnw[lane + 64];
    float lb0 = lnb[lane], lb1 = lnb[lane + 64];
    for (int rr = 0; rr < RROWS / 4; rr++) {
        int r = rr * 4 + wv;
        int row = base + r;
        if (row >= NN) continue;
        float v0 = stage[r * SSTR + lane] + b0v;
        float v1 = stage[r * SSTR + lane + 64] + b1v;
        float s = v0 + v1, s2 = v0 * v0 + v1 * v1;
#pragma unroll
        for (int o2 = 32; o2 > 0; o2 >>= 1) {
            s  += __shfl_xor(s,  o2, 64);
            s2 += __shfl_xor(s2, o2, 64);
        }
        float mu = s * (1.0f / CDIM);
        float var = s2 * (1.0f / CDIM) - mu * mu;
        float rs = rsqrtf(var + 1e-5f);
        float o0 = fmaxf((v0 - mu) * rs * lw0 + lb0, 0.0f);
        float o1 = fmaxf((v1 - mu) * rs * lw1 + lb1, 0.0f);
        size_t oi = (size_t)row * CDIM;
        xnext[oi + lane] = o0;
        xnext[oi + lane + 64] = o1;
        if (xnext_bf) {
            xnext_bf[oi + lane] = f2bf(o0);
            xnext_bf[oi + lane + 64] = f2bf(o1);
        }
    }
}

extern "C" void kernel_launch(void* const* d_in, const int* in_sizes, int n_in,
                              void* d_out, int out_size, void* d_ws, size_t ws_size,
                              hipStream_t stream)
{
    const float* x_a      = (const float*)d_in[0];
    const float* x_b      = (const float*)d_in[1];
    const float* schema_x = (const float*)d_in[2];
    const int*   e_ab     = (const int*)d_in[3];
    const int*   e_ba     = (const int*)d_in[4];
    const int*   e_aa     = (const int*)d_in[5];
    const int*   sei      = (const int*)d_in[6];
    const float* preW     = (const float*)d_in[7];
    const float* preb     = (const float*)d_in[8];
    const float* gcnW     = (const float*)d_in[9];
    const float* gcnb     = (const float*)d_in[10];
    const float* coW      = (const float*)d_in[11];
    const float* cob      = (const float*)d_in[12];
    const float* bases    = (const float*)d_in[13];
    const float* sbias    = (const float*)d_in[14];
    const float* lnw      = (const float*)d_in[15];
    const float* lnb      = (const float*)d_in[16];

    float* out     = (float*)d_out;
    float* out_xa  = out;
    float* out_xb  = out + 6400000;
    float* out_sf  = out + 12800000;
    float* out_ori = out + 12800512;

    float* ws = (float*)d_ws;
    int*      col    = (int*)ws;
    int*      rowptr = (int*)(ws + 2400000);
    int*      bcnt   = (int*)(ws + 6150016);
    int*      boff   = (int*)(ws + 6150320);
    int*      bcur   = (int*)(ws + 6150624);
    float* xa_buf = ws + 6150928;
    unsigned* buf = (unsigned*)xa_buf;     // aliases xa_buf head; dead before layer-0 fuse_a
    float* xb_buf = ws + 12550928;
    unsigned short* Wbf = (unsigned short*)(ws + 18950928);
    float* coeffs = ws + 19000080;
    unsigned short* xa_bf0 = (unsigned short*)(ws + 19000112);
    unsigned short* xb_bf0 = (unsigned short*)(ws + 22200176);
    unsigned short* xa_bf1 = (unsigned short*)(ws + 25400240);
    unsigned short* xb_bf1 = (unsigned short*)(ws + 28600304);

    schema_kernel<<<1, 512, 0, stream>>>(schema_x, sei, preW, preb, gcnW, gcnb,
                                         coW, cob, out_sf, out_ori, coeffs);
    build_w_kernel<<<384, 256, 0, stream>>>(bases, coeffs, Wbf);

    tobf16_kernel<<<(NA * CDIM / 4 + 255) / 256, 256, 0, stream>>>(x_a, xa_bf0, NA * CDIM);
    tobf16_kernel<<<(NB * CDIM / 4 + 255) / 256, 256, 0, stream>>>(x_b, xb_bf0, NB * CDIM);
    zero_rows_kernel<<<1, 256, 0, stream>>>(xa_bf0, xb_bf0, xa_bf1, xb_bf1);

    hipMemsetAsync(bcnt, 0, 3 * NBUCK * sizeof(int), stream);
    dim3 cgrid((EDGES + 4095) / 4096, 3);
    bucket_count_kernel<<<cgrid, 256, 0, stream>>>(e_ab, e_ba, e_aa, bcnt);
    bucket_scan_kernel<<<1, 32, 0, stream>>>(bcnt, boff, bcur);
    bucket_partition_kernel<<<cgrid, 256, 0, stream>>>(e_ab, e_ba, e_aa, bcur, buf);
    dim3 sgrid(NBUCK, 3);
    bucket_scatter_kernel<<<sgrid, 256, 0, stream>>>(buf, boff, rowptr, col);

    const int* rp_ab = rowptr;
    const int* rp_ba = rowptr + RPSTR;
    const int* rp_aa = rowptr + 2 * RPSTR;
    const int* col_ab = col;
    const int* col_ba = col + EDGES;
    const int* col_aa = col + 2 * EDGES;

    const int fgrid = (NN + RROWS - 1) / RROWS;   // 1563

    for (int l = 0; l < 2; l++) {
        const float* xa_cur = (l == 0) ? x_a : xa_buf;
        const float* xb_cur = (l == 0) ? x_b : xb_buf;
        const unsigned short* xa_bf = (l == 0) ? xa_bf0 : xa_bf1;
        const unsigned short* xb_bf = (l == 0) ? xb_bf0 : xb_bf1;
        const unsigned short* Wab = Wbf + (size_t)(l * 3 + 0) * 16384;
        const unsigned short* Wba = Wbf + (size_t)(l * 3 + 1) * 16384;
        const unsigned short* Waa = Wbf + (size_t)(l * 3 + 2) * 16384;
        float* xa_nxt = (l == 0) ? xa_buf : out_xa;
        float* xb_nxt = (l == 0) ? xb_buf : out_xb;
        unsigned short* xa_nbf = (l == 0) ? xa_bf1 : nullptr;
        unsigned short* xb_nbf = (l == 0) ? xb_bf1 : nullptr;

        fuse_b_kernel<<<fgrid, 256, 0, stream>>>(
            xa_bf, xb_cur, rp_ab, col_ab, Wab,
            sbias + (size_t)(l * 3 + 0) * 128,
            lnw + (size_t)(l * 2 + 1) * 128, lnb + (size_t)(l * 2 + 1) * 128,
            xb_nxt, xb_nbf);
        fuse_a_kernel<<<fgrid, 256, 0, stream>>>(
            xb_bf, rp_ba, col_ba, xa_bf, rp_aa, col_aa, xa_cur,
            Wba, Waa,
            sbias + (size_t)(l * 3 + 1) * 128, sbias + (size_t)(l * 3 + 2) * 128,
            lnw + (size_t)(l * 2 + 0) * 128, lnb + (size_t)(l * 2 + 0) * 128,
            xa_nxt, xa_nbf);
    }
}

// Round 8
// 576.508 us; speedup vs baseline: 4.7113x; 1.0225x over previous
//
#include <hip/hip_runtime.h>

#define NA 50000
#define NB 50000
#define NN 50000
#define CDIM 128
#define EDGES 800000
#define SS 8
#define INDIM 64
#define HDIM 64
#define NBASES 8
#define NBUCK 98
#define BSH 9

#define RROWS 32
#define USTR 136   // ushort stride (pad) for bf16 U/V tiles
#define SSTR 129   // float stride for acc staging

typedef __attribute__((ext_vector_type(8))) short bf16x8;
typedef __attribute__((ext_vector_type(4))) float f32x4;

// ---------------------------------------------------------------------------
// Workspace layout (4-byte element offsets) — round-1 verified layout:
//   0         col      [3*E]        int
//   2400000   rowptr   [3*(NN+1)]   int
//   2550016   buf      [3*E]        uint
//   4950016   bcnt     [3*98]       int      (pad 304)
//   4950320   boff     [3*99]       int      (pad 304)
//   4950624   bcur     [3*98]       int      (pad 304)
//   4950928   xa_buf   [NA*128]     float
//   11350928  xb_buf   [NB*128]     float
//   17750928  Wbf      ushort[6*128*128]  (bf16, row-major [j][k])
//   17800080  coeffs   [3*8]        float  (pad to 17800112)
//   17800112  xa_bf0   ushort[(NN+1)*128]   (row NN = zero row)
//   21000176  xb_bf0   ushort[(NN+1)*128]
//   24200240  xa_bf1   ushort[(NN+1)*128]
//   27400304  xb_bf1   ushort[(NN+1)*128]
//   30600368  end (~122 MB)
// ---------------------------------------------------------------------------

__device__ __forceinline__ unsigned short f2bf(float f) {
    unsigned u = __float_as_uint(f);
    return (unsigned short)((u + 0x7FFFu + ((u >> 16) & 1u)) >> 16);
}

// Schema GCN + coefficient computation. One block, 512 threads.
__global__ __launch_bounds__(512) void schema_kernel(
    const float* __restrict__ schema_x, const int* __restrict__ sei,
    const float* __restrict__ preW, const float* __restrict__ preb,
    const float* __restrict__ gcnW, const float* __restrict__ gcnb,
    const float* __restrict__ coW, const float* __restrict__ cob,
    float* __restrict__ out_sf, float* __restrict__ out_ori,
    float* __restrict__ coeffs)
{
    __shared__ float h[SS][HDIM];
    __shared__ float xw[SS][HDIM];
    __shared__ float sf[SS][HDIM];
    __shared__ float deg[SS];
    __shared__ float nrm[32];
    __shared__ int es[32], ed[32];

    int t = threadIdx.x;
    int i = t >> 6, j = t & 63;

    float acc = preb[j];
    for (int k = 0; k < INDIM; k++) acc += schema_x[i * INDIM + k] * preW[j * INDIM + k];
    h[i][j] = acc;
    out_ori[i * HDIM + j] = acc;
    if (t < SS) deg[t] = 0.0f;
    __syncthreads();

    if (t < 32) {
        int s, d;
        if (t < 24) { s = sei[t]; d = sei[24 + t]; }
        else        { s = t - 24; d = t - 24; }
        es[t] = s; ed[t] = d;
        atomicAdd(&deg[d], 1.0f);
    }
    __syncthreads();
    if (t < 32) {
        nrm[t] = rsqrtf(fmaxf(deg[es[t]], 1e-12f)) * rsqrtf(fmaxf(deg[ed[t]], 1e-12f));
    }
    float a2 = 0.0f;
    for (int k = 0; k < HDIM; k++) a2 += h[i][k] * gcnW[j * HDIM + k];
    xw[i][j] = a2;
    __syncthreads();

    float o = gcnb[j];
    for (int e = 0; e < 32; e++) {
        if (ed[e] == i) o += xw[es[e]][j] * nrm[e];
    }
    float s = fmaxf(o, 0.0f);
    sf[i][j] = s;
    out_sf[i * HDIM + j] = s;
    __syncthreads();

    if (t < 24) {
        int ty = t >> 3, ii = t & 7;
        int srow = (ty == 1) ? 1 : 0;
        int drow = (ty == 0) ? 1 : 0;
        float a = cob[ii];
        for (int k = 0; k < HDIM; k++) a += sf[srow][k] * coW[ii * (2 * HDIM) + k];
        for (int k = 0; k < HDIM; k++) a += sf[drow][k] * coW[ii * (2 * HDIM) + HDIM + k];
        coeffs[ty * 8 + ii] = a;
    }
}

// W in bf16, row-major [mat][j][k] (B-operand needs contiguous k per row)
__global__ __launch_bounds__(256) void build_w_kernel(
    const float* __restrict__ bases, const float* __restrict__ coeffs,
    unsigned short* __restrict__ Wbf)
{
    int idx = blockIdx.x * blockDim.x + threadIdx.x;   // < 6*16384
    int lt = idx >> 14;
    int jk = idx & 16383;
    int l = lt / 3, ty = lt % 3;
    float acc = 0.0f;
#pragma unroll
    for (int i = 0; i < NBASES; i++)
        acc += coeffs[ty * 8 + i] * bases[((size_t)(l * NBASES + i) << 14) + jk];
    Wbf[idx] = f2bf(acc);
}

__global__ __launch_bounds__(256) void tobf16_kernel(
    const float* __restrict__ in, unsigned short* __restrict__ out, int n)
{
    int i = (blockIdx.x * 256 + threadIdx.x) * 4;
    if (i >= n) return;
    float4 f = *(const float4*)(in + i);
    ushort4 o;
    o.x = f2bf(f.x); o.y = f2bf(f.y); o.z = f2bf(f.z); o.w = f2bf(f.w);
    *(ushort4*)(out + i) = o;
}

__global__ __launch_bounds__(256) void zero_rows_kernel(
    unsigned short* a0, unsigned short* b0, unsigned short* a1, unsigned short* b1)
{
    int t = threadIdx.x;
    int tab = t >> 6, w = t & 63;
    unsigned short* p = (tab == 0) ? a0 : (tab == 1) ? b0 : (tab == 2) ? a1 : b1;
    ((unsigned*)(p + (size_t)NN * CDIM))[w] = 0u;
}

// ---------------- locality-aware CSR build ----------------------------------

__global__ __launch_bounds__(256) void bucket_count_kernel(
    const int* __restrict__ ab, const int* __restrict__ ba,
    const int* __restrict__ aa, int* __restrict__ bcnt)
{
    __shared__ int h[NBUCK];
    int t = threadIdx.x;
    int ty = blockIdx.y;
    const int* ei = (ty == 0) ? ab : (ty == 1) ? ba : aa;
    if (t < NBUCK) h[t] = 0;
    __syncthreads();
    int cb = blockIdx.x * 4096;
    int en = min(cb + 4096, EDGES);
    for (int e = cb + t; e < en; e += 256)
        atomicAdd(&h[ei[EDGES + e] >> BSH], 1);
    __syncthreads();
    if (t < NBUCK) atomicAdd(&bcnt[ty * NBUCK + t], h[t]);
}

__global__ __launch_bounds__(32) void bucket_scan_kernel(
    const int* __restrict__ bcnt, int* __restrict__ boff, int* __restrict__ bcur)
{
    int t = threadIdx.x;
    if (t < 3) {
        int run = 0;
        for (int i = 0; i < NBUCK; i++) {
            int c = bcnt[t * NBUCK + i];
            boff[t * (NBUCK + 1) + i] = run;
            bcur[t * NBUCK + i] = run;
            run += c;
        }
        boff[t * (NBUCK + 1) + NBUCK] = run;
    }
}

__global__ __launch_bounds__(256) void bucket_partition_kernel(
    const int* __restrict__ ab, const int* __restrict__ ba,
    const int* __restrict__ aa, int* __restrict__ bcur,
    unsigned* __restrict__ buf)
{
    __shared__ int h[NBUCK];
    __shared__ int basearr[NBUCK];
    __shared__ int cur[NBUCK];
    int t = threadIdx.x;
    int ty = blockIdx.y;
    const int* ei = (ty == 0) ? ab : (ty == 1) ? ba : aa;
    if (t < NBUCK) h[t] = 0;
    __syncthreads();
    int cb = blockIdx.x * 4096;
    int en = min(cb + 4096, EDGES);
    for (int e = cb + t; e < en; e += 256)
        atomicAdd(&h[ei[EDGES + e] >> BSH], 1);
    __syncthreads();
    if (t < NBUCK) {
        basearr[t] = atomicAdd(&bcur[ty * NBUCK + t], h[t]);
        cur[t] = 0;
    }
    __syncthreads();
    for (int e = cb + t; e < en; e += 256) {
        int src = ei[e], dst = ei[EDGES + e];
        int b = dst >> BSH;
        int r = atomicAdd(&cur[b], 1);
        buf[(size_t)ty * EDGES + basearr[b] + r] =
            ((unsigned)(dst & 511) << 16) | (unsigned)src;
    }
}

__global__ __launch_bounds__(256) void bucket_scatter_kernel(
    const unsigned* __restrict__ buf, const int* __restrict__ boff,
    int* __restrict__ rowptr, int* __restrict__ col)
{
    __shared__ int cnt[512];
    __shared__ int part[256];
    int t = threadIdx.x;
    int b = blockIdx.x, ty = blockIdx.y;
    int nstart = boff[ty * (NBUCK + 1) + b];
    int nend   = boff[ty * (NBUCK + 1) + b + 1];
    int n = nend - nstart;
    cnt[t] = 0; cnt[t + 256] = 0;
    __syncthreads();
    const unsigned* bb = buf + (size_t)ty * EDGES + nstart;
    for (int i = t; i < n; i += 256)
        atomicAdd(&cnt[bb[i] >> 16], 1);
    __syncthreads();
    int a0 = cnt[2 * t], a1 = cnt[2 * t + 1];
    int s = a0 + a1;
    part[t] = s;
    __syncthreads();
    for (int off = 1; off < 256; off <<= 1) {
        int v = (t >= off) ? part[t - off] : 0;
        __syncthreads();
        part[t] += v;
        __syncthreads();
    }
    int excl = part[t] - s;
    int p0 = excl, p1 = excl + a0;
    cnt[2 * t] = p0; cnt[2 * t + 1] = p1;
    int row0 = (b << BSH) + 2 * t;
    int rbase = ty * (NN + 1);
    if (row0 < NN)     rowptr[rbase + row0] = nstart + p0;
    if (row0 + 1 < NN) rowptr[rbase + row0 + 1] = nstart + p1;
    if (b == NBUCK - 1 && t == 255) rowptr[rbase + NN] = EDGES;
    __syncthreads();
    int* cc = col + (size_t)ty * EDGES + nstart;
    for (int i = t; i < n; i += 256) {
        unsigned pk = bb[i];
        int r = atomicAdd(&cnt[pk >> 16], 1);
        cc[r] = (int)(pk & 0xFFFFu);
    }
}

// ---------------- fused gather + MFMA matmul + LN -> ReLU -------------------

#define ACC4(gv, vv)                                            \
    gv.x += __uint_as_float((vv).x << 16);                      \
    gv.y += __uint_as_float((vv).x & 0xffff0000u);              \
    gv.z += __uint_as_float((vv).y << 16);                      \
    gv.w += __uint_as_float((vv).y & 0xffff0000u);

// b-side: mean(bf x_a) + x_b -> bf16 U; U @ W^T (MFMA) + bias -> LN -> ReLU
// Gather processes TWO rows per iteration with all 32 data loads issued
// before any consumption (deep MLP under latency).
__global__ __launch_bounds__(256, 4) void fuse_b_kernel(
    const unsigned short* __restrict__ xsrc, const float* __restrict__ xdst,
    const int* __restrict__ rowptr, const int* __restrict__ col,
    const unsigned short* __restrict__ Wbf, const float* __restrict__ bias,
    const float* __restrict__ lnw, const float* __restrict__ lnb,
    float* __restrict__ xnext, unsigned short* __restrict__ xnext_bf)
{
    __shared__ float4 smraw[1032];   // max(RROWS*USTR*2, RROWS*SSTR*4) = 16512 B
    unsigned short* Ubf = (unsigned short*)smraw;
    float* stage = (float*)smraw;
    int t = threadIdx.x;
    int base = blockIdx.x * RROWS;
    int wv = t >> 6;
    int lane = t & 63;
    int half = lane >> 5, cl = lane & 31;
    int off = cl << 2;

    for (int k = 0; k < 4; k++) {
        int rA = (2 * k) * 4 + wv;
        int rB = rA + 4;
        int rowA = base + rA, rowB = base + rB;
        int sA = 0, eA = 0, sB = 0, eB = 0;
        if (rowA < NN) { sA = rowptr[rowA]; eA = rowptr[rowA + 1]; }
        if (rowB < NN) { sB = rowptr[rowB]; eB = rowptr[rowB + 1]; }
        int csA[16], csB[16];
#pragma unroll
        for (int j = 0; j < 16; j++) {
            int sl = sA + 2 * j + half;
            int cc = col[min(sl, EDGES - 1)];
            csA[j] = (sl < eA) ? cc : NN;
        }
#pragma unroll
        for (int j = 0; j < 16; j++) {
            int sl = sB + 2 * j + half;
            int cc = col[min(sl, EDGES - 1)];
            csB[j] = (sl < eB) ? cc : NN;
        }
        uint2 vA[16], vB[16];
#pragma unroll
        for (int j = 0; j < 16; j++)
            vA[j] = *(const uint2*)(xsrc + (size_t)csA[j] * CDIM + off);
#pragma unroll
        for (int j = 0; j < 16; j++)
            vB[j] = *(const uint2*)(xsrc + (size_t)csB[j] * CDIM + off);
        float4 gA = make_float4(0.f, 0.f, 0.f, 0.f);
        float4 gB = make_float4(0.f, 0.f, 0.f, 0.f);
#pragma unroll
        for (int j = 0; j < 16; j++) { ACC4(gA, vA[j]) }
#pragma unroll
        for (int j = 0; j < 16; j++) { ACC4(gB, vB[j]) }
        // rare tails (deg > 32)
        for (int b2 = sA + 32; b2 < eA; b2 += 16) {
#pragma unroll
            for (int j = 0; j < 8; j++) {
                int sl = b2 + 2 * j + half;
                int cc = col[min(sl, EDGES - 1)];
                int id = (sl < eA) ? cc : NN;
                uint2 vv = *(const uint2*)(xsrc + (size_t)id * CDIM + off);
                ACC4(gA, vv)
            }
        }
        for (int b2 = sB + 32; b2 < eB; b2 += 16) {
#pragma unroll
            for (int j = 0; j < 8; j++) {
                int sl = b2 + 2 * j + half;
                int cc = col[min(sl, EDGES - 1)];
                int id = (sl < eB) ? cc : NN;
                uint2 vv = *(const uint2*)(xsrc + (size_t)id * CDIM + off);
                ACC4(gB, vv)
            }
        }
        gA.x += __shfl_xor(gA.x, 32, 64);
        gA.y += __shfl_xor(gA.y, 32, 64);
        gA.z += __shfl_xor(gA.z, 32, 64);
        gA.w += __shfl_xor(gA.w, 32, 64);
        gB.x += __shfl_xor(gB.x, 32, 64);
        gB.y += __shfl_xor(gB.y, 32, 64);
        gB.z += __shfl_xor(gB.z, 32, 64);
        gB.w += __shfl_xor(gB.w, 32, 64);
        if (half == 0) {
            ushort4 oA = make_ushort4(0, 0, 0, 0), oB = oA;
            if (rowA < NN) {
                float inv = 1.0f / (float)max(eA - sA, 1);
                const float4 xv = *(const float4*)(xdst + (size_t)rowA * CDIM + off);
                oA.x = f2bf(gA.x * inv + xv.x);
                oA.y = f2bf(gA.y * inv + xv.y);
                oA.z = f2bf(gA.z * inv + xv.z);
                oA.w = f2bf(gA.w * inv + xv.w);
            }
            if (rowB < NN) {
                float inv = 1.0f / (float)max(eB - sB, 1);
                const float4 xv = *(const float4*)(xdst + (size_t)rowB * CDIM + off);
                oB.x = f2bf(gB.x * inv + xv.x);
                oB.y = f2bf(gB.y * inv + xv.y);
                oB.z = f2bf(gB.z * inv + xv.z);
                oB.w = f2bf(gB.w * inv + xv.w);
            }
            *(ushort4*)&Ubf[rA * USTR + off] = oA;
            *(ushort4*)&Ubf[rB * USTR + off] = oB;
        }
    }
    __syncthreads();

    // MFMA: wave wv -> N-tiles {2wv, 2wv+1}, M-tiles {0,1}
    int qd = lane >> 4;
    int ln16 = lane & 15;
    f32x4 acc00 = {0.f,0.f,0.f,0.f}, acc01 = acc00, acc10 = acc00, acc11 = acc00;
#pragma unroll
    for (int ks = 0; ks < 4; ks++) {
        int koff = ks * 32 + qd * 8;
        bf16x8 a0 = *(const bf16x8*)&Ubf[(ln16) * USTR + koff];
        bf16x8 a1 = *(const bf16x8*)&Ubf[(16 + ln16) * USTR + koff];
        bf16x8 b0 = *(const bf16x8*)&Wbf[(size_t)((2 * wv + 0) * 16 + ln16) * CDIM + koff];
        bf16x8 b1 = *(const bf16x8*)&Wbf[(size_t)((2 * wv + 1) * 16 + ln16) * CDIM + koff];
        acc00 = __builtin_amdgcn_mfma_f32_16x16x32_bf16(a0, b0, acc00, 0, 0, 0);
        acc01 = __builtin_amdgcn_mfma_f32_16x16x32_bf16(a0, b1, acc01, 0, 0, 0);
        acc10 = __builtin_amdgcn_mfma_f32_16x16x32_bf16(a1, b0, acc10, 0, 0, 0);
        acc11 = __builtin_amdgcn_mfma_f32_16x16x32_bf16(a1, b1, acc11, 0, 0, 0);
    }
    __syncthreads();   // all MFMA reads of Ubf done before stage overwrites it
    // C/D layout: col = lane&15 (in tile), row = quad*4 + reg
    {
        int c0 = (2 * wv + 0) * 16 + ln16;
        int c1 = (2 * wv + 1) * 16 + ln16;
#pragma unroll
        for (int i = 0; i < 4; i++) {
            int r0 = qd * 4 + i;
            stage[r0 * SSTR + c0] = acc00[i];
            stage[r0 * SSTR + c1] = acc01[i];
            stage[(16 + r0) * SSTR + c0] = acc10[i];
            stage[(16 + r0) * SSTR + c1] = acc11[i];
        }
    }
    __syncthreads();

    float b0v = bias[lane], b1v = bias[lane + 64];
    float lw0 = lnw[lane], lw1 = lnw[lane + 64];
    float lb0 = lnb[lane], lb1 = lnb[lane + 64];
    for (int rr = 0; rr < RROWS / 4; rr++) {
        int r = rr * 4 + wv;
        int row = base + r;
        if (row >= NN) continue;
        float v0 = stage[r * SSTR + lane] + b0v;
        float v1 = stage[r * SSTR + lane + 64] + b1v;
        float s = v0 + v1, s2 = v0 * v0 + v1 * v1;
#pragma unroll
        for (int o2 = 32; o2 > 0; o2 >>= 1) {
            s  += __shfl_xor(s,  o2, 64);
            s2 += __shfl_xor(s2, o2, 64);
        }
        float mu = s * (1.0f / CDIM);
        float var = s2 * (1.0f / CDIM) - mu * mu;
        float rs = rsqrtf(var + 1e-5f);
        float o0 = fmaxf((v0 - mu) * rs * lw0 + lb0, 0.0f);
        float o1 = fmaxf((v1 - mu) * rs * lw1 + lb1, 0.0f);
        size_t oi = (size_t)row * CDIM;
        xnext[oi + lane] = o0;
        xnext[oi + lane + 64] = o1;
        if (xnext_bf) {
            xnext_bf[oi + lane] = f2bf(o0);
            xnext_bf[oi + lane + 64] = f2bf(o1);
        }
    }
}

// a-side: U = mean_ba(bf x_b)+x_a, V = mean_aa(bf x_a)+x_a;
// out = U@W1^T + V@W2^T + b1 + b2 (MFMA) -> LN -> ReLU
// Both tables' 16 data loads are issued back-to-back (32 outstanding) before
// either is consumed — deep MLP under latency.
__global__ __launch_bounds__(256, 4) void fuse_a_kernel(
    const unsigned short* __restrict__ xsrc1, const int* __restrict__ rowptr1, const int* __restrict__ col1,
    const unsigned short* __restrict__ xsrc2, const int* __restrict__ rowptr2, const int* __restrict__ col2,
    const float* __restrict__ xdst,
    const unsigned short* __restrict__ W1bf, const unsigned short* __restrict__ W2bf,
    const float* __restrict__ bias1, const float* __restrict__ bias2,
    const float* __restrict__ lnw, const float* __restrict__ lnb,
    float* __restrict__ xnext, unsigned short* __restrict__ xnext_bf)
{
    __shared__ float4 smraw[1088];   // max(2*RROWS*USTR*2, RROWS*SSTR*4) = 17408 B
    unsigned short* Ubf = (unsigned short*)smraw;
    unsigned short* Vbf = Ubf + RROWS * USTR;
    float* stage = (float*)smraw;
    int t = threadIdx.x;
    int base = blockIdx.x * RROWS;
    int wv = t >> 6;
    int lane = t & 63;
    int half = lane >> 5, cl = lane & 31;
    int off = cl << 2;

    for (int rr = 0; rr < 8; rr++) {
        int r = rr * 4 + wv;
        int row = base + r;
        int s1 = 0, e1 = 0, s2 = 0, e2 = 0;
        if (row < NN) {
            s1 = rowptr1[row]; e1 = rowptr1[row + 1];
            s2 = rowptr2[row]; e2 = rowptr2[row + 1];
        }
        int cs1[16], cs2[16];
#pragma unroll
        for (int j = 0; j < 16; j++) {
            int sl = s1 + 2 * j + half;
            int cc = col1[min(sl, EDGES - 1)];
            cs1[j] = (sl < e1) ? cc : NN;
        }
#pragma unroll
        for (int j = 0; j < 16; j++) {
            int sl = s2 + 2 * j + half;
            int cc = col2[min(sl, EDGES - 1)];
            cs2[j] = (sl < e2) ? cc : NN;
        }
        uint2 v1[16], v2[16];
#pragma unroll
        for (int j = 0; j < 16; j++)
            v1[j] = *(const uint2*)(xsrc1 + (size_t)cs1[j] * CDIM + off);
#pragma unroll
        for (int j = 0; j < 16; j++)
            v2[j] = *(const uint2*)(xsrc2 + (size_t)cs2[j] * CDIM + off);
        float4 g1 = make_float4(0.f, 0.f, 0.f, 0.f);
        float4 g2 = make_float4(0.f, 0.f, 0.f, 0.f);
#pragma unroll
        for (int j = 0; j < 16; j++) { ACC4(g1, v1[j]) }
#pragma unroll
        for (int j = 0; j < 16; j++) { ACC4(g2, v2[j]) }
        // rare tails (deg > 32)
        for (int b2 = s1 + 32; b2 < e1; b2 += 16) {
#pragma unroll
            for (int j = 0; j < 8; j++) {
                int sl = b2 + 2 * j + half;
                int cc = col1[min(sl, EDGES - 1)];
                int id = (sl < e1) ? cc : NN;
                uint2 vv = *(const uint2*)(xsrc1 + (size_t)id * CDIM + off);
                ACC4(g1, vv)
            }
        }
        for (int b2 = s2 + 32; b2 < e2; b2 += 16) {
#pragma unroll
            for (int j = 0; j < 8; j++) {
                int sl = b2 + 2 * j + half;
                int cc = col2[min(sl, EDGES - 1)];
                int id = (sl < e2) ? cc : NN;
                uint2 vv = *(const uint2*)(xsrc2 + (size_t)id * CDIM + off);
                ACC4(g2, vv)
            }
        }
        g1.x += __shfl_xor(g1.x, 32, 64);
        g1.y += __shfl_xor(g1.y, 32, 64);
        g1.z += __shfl_xor(g1.z, 32, 64);
        g1.w += __shfl_xor(g1.w, 32, 64);
        g2.x += __shfl_xor(g2.x, 32, 64);
        g2.y += __shfl_xor(g2.y, 32, 64);
        g2.z += __shfl_xor(g2.z, 32, 64);
        g2.w += __shfl_xor(g2.w, 32, 64);
        if (half == 0) {
            ushort4 ou = make_ushort4(0, 0, 0, 0), ov = ou;
            if (row < NN) {
                const float4 xv = *(const float4*)(xdst + (size_t)row * CDIM + off);
                float i1 = 1.0f / (float)max(e1 - s1, 1);
                float i2 = 1.0f / (float)max(e2 - s2, 1);
                ou.x = f2bf(g1.x * i1 + xv.x); ou.y = f2bf(g1.y * i1 + xv.y);
                ou.z = f2bf(g1.z * i1 + xv.z); ou.w = f2bf(g1.w * i1 + xv.w);
                ov.x = f2bf(g2.x * i2 + xv.x); ov.y = f2bf(g2.y * i2 + xv.y);
                ov.z = f2bf(g2.z * i2 + xv.z); ov.w = f2bf(g2.w * i2 + xv.w);
            }
            *(ushort4*)&Ubf[r * USTR + off] = ou;
            *(ushort4*)&Vbf[r * USTR + off] = ov;
        }
    }
    __syncthreads();

    int qd = lane >> 4;
    int ln16 = lane & 15;
    f32x4 acc00 = {0.f,0.f,0.f,0.f}, acc01 = acc00, acc10 = acc00, acc11 = acc00;
#pragma unroll
    for (int ks = 0; ks < 4; ks++) {
        int koff = ks * 32 + qd * 8;
        bf16x8 aU0 = *(const bf16x8*)&Ubf[(ln16) * USTR + koff];
        bf16x8 aU1 = *(const bf16x8*)&Ubf[(16 + ln16) * USTR + koff];
        bf16x8 aV0 = *(const bf16x8*)&Vbf[(ln16) * USTR + koff];
        bf16x8 aV1 = *(const bf16x8*)&Vbf[(16 + ln16) * USTR + koff];
        size_t wrow0 = (size_t)((2 * wv + 0) * 16 + ln16) * CDIM + koff;
        size_t wrow1 = (size_t)((2 * wv + 1) * 16 + ln16) * CDIM + koff;
        bf16x8 b10 = *(const bf16x8*)&W1bf[wrow0];
        bf16x8 b11 = *(const bf16x8*)&W1bf[wrow1];
        bf16x8 b20 = *(const bf16x8*)&W2bf[wrow0];
        bf16x8 b21 = *(const bf16x8*)&W2bf[wrow1];
        acc00 = __builtin_amdgcn_mfma_f32_16x16x32_bf16(aU0, b10, acc00, 0, 0, 0);
        acc01 = __builtin_amdgcn_mfma_f32_16x16x32_bf16(aU0, b11, acc01, 0, 0, 0);
        acc10 = __builtin_amdgcn_mfma_f32_16x16x32_bf16(aU1, b10, acc10, 0, 0, 0);
        acc11 = __builtin_amdgcn_mfma_f32_16x16x32_bf16(aU1, b11, acc11, 0, 0, 0);
        acc00 = __builtin_amdgcn_mfma_f32_16x16x32_bf16(aV0, b20, acc00, 0, 0, 0);
        acc01 = __builtin_amdgcn_mfma_f32_16x16x32_bf16(aV0, b21, acc01, 0, 0, 0);
        acc10 = __builtin_amdgcn_mfma_f32_16x16x32_bf16(aV1, b20, acc10, 0, 0, 0);
        acc11 = __builtin_amdgcn_mfma_f32_16x16x32_bf16(aV1, b21, acc11, 0, 0, 0);
    }
    __syncthreads();   // all MFMA reads of Ubf/Vbf done before stage overwrites them
    {
        int c0 = (2 * wv + 0) * 16 + ln16;
        int c1 = (2 * wv + 1) * 16 + ln16;
#pragma unroll
        for (int i = 0; i < 4; i++) {
            int r0 = qd * 4 + i;
            stage[r0 * SSTR + c0] = acc00[i];
            stage[r0 * SSTR + c1] = acc01[i];
            stage[(16 + r0) * SSTR + c0] = acc10[i];
            stage[(16 + r0) * SSTR + c1] = acc11[i];
        }
    }
    __syncthreads();

    float b0v = bias1[lane] + bias2[lane];
    float b1v = bias1[lane + 64] + bias2[lane + 64];
    float lw0 = lnw[lane], lw1 = lnw[lane + 64];
    float lb0 = lnb[lane], lb1 = lnb[lane + 64];
    for (int rr = 0; rr < RROWS / 4; rr++) {
        int r = rr * 4 + wv;
        int row = base + r;
        if (row >= NN) continue;
        float v0 = stage[r * SSTR + lane] + b0v;
        float v1 = stage[r * SSTR + lane + 64] + b1v;
        float s = v0 + v1, s2 = v0 * v0 + v1 * v1;
#pragma unroll
        for (int o2 = 32; o2 > 0; o2 >>= 1) {
            s  += __shfl_xor(s,  o2, 64);
            s2 += __shfl_xor(s2, o2, 64);
        }
        float mu = s * (1.0f / CDIM);
        float var = s2 * (1.0f / CDIM) - mu * mu;
        float rs = rsqrtf(var + 1e-5f);
        float o0 = fmaxf((v0 - mu) * rs * lw0 + lb0, 0.0f);
        float o1 = fmaxf((v1 - mu) * rs * lw1 + lb1, 0.0f);
        size_t oi = (size_t)row * CDIM;
        xnext[oi + lane] = o0;
        xnext[oi + lane + 64] = o1;
        if (xnext_bf) {
            xnext_bf[oi + lane] = f2bf(o0);
            xnext_bf[oi + lane + 64] = f2bf(o1);
        }
    }
}

extern "C" void kernel_launch(void* const* d_in, const int* in_sizes, int n_in,
                              void* d_out, int out_size, void* d_ws, size_t ws_size,
                              hipStream_t stream)
{
    const float* x_a      = (const float*)d_in[0];
    const float* x_b      = (const float*)d_in[1];
    const float* schema_x = (const float*)d_in[2];
    const int*   e_ab     = (const int*)d_in[3];
    const int*   e_ba     = (const int*)d_in[4];
    const int*   e_aa     = (const int*)d_in[5];
    const int*   sei      = (const int*)d_in[6];
    const float* preW     = (const float*)d_in[7];
    const float* preb     = (const float*)d_in[8];
    const float* gcnW     = (const float*)d_in[9];
    const float* gcnb     = (const float*)d_in[10];
    const float* coW      = (const float*)d_in[11];
    const float* cob      = (const float*)d_in[12];
    const float* bases    = (const float*)d_in[13];
    const float* sbias    = (const float*)d_in[14];
    const float* lnw      = (const float*)d_in[15];
    const float* lnb      = (const float*)d_in[16];

    float* out     = (float*)d_out;
    float* out_xa  = out;
    float* out_xb  = out + 6400000;
    float* out_sf  = out + 12800000;
    float* out_ori = out + 12800512;

    float* ws = (float*)d_ws;
    int*      col    = (int*)ws;
    int*      rowptr = (int*)(ws + 2400000);
    unsigned* buf    = (unsigned*)(ws + 2550016);
    int*      bcnt   = (int*)(ws + 4950016);
    int*      boff   = (int*)(ws + 4950320);
    int*      bcur   = (int*)(ws + 4950624);
    float* xa_buf = ws + 4950928;
    float* xb_buf = ws + 11350928;
    unsigned short* Wbf = (unsigned short*)(ws + 17750928);
    float* coeffs = ws + 17800080;
    unsigned short* xa_bf0 = (unsigned short*)(ws + 17800112);
    unsigned short* xb_bf0 = (unsigned short*)(ws + 21000176);
    unsigned short* xa_bf1 = (unsigned short*)(ws + 24200240);
    unsigned short* xb_bf1 = (unsigned short*)(ws + 27400304);

    schema_kernel<<<1, 512, 0, stream>>>(schema_x, sei, preW, preb, gcnW, gcnb,
                                         coW, cob, out_sf, out_ori, coeffs);
    build_w_kernel<<<384, 256, 0, stream>>>(bases, coeffs, Wbf);

    tobf16_kernel<<<(NA * CDIM / 4 + 255) / 256, 256, 0, stream>>>(x_a, xa_bf0, NA * CDIM);
    tobf16_kernel<<<(NB * CDIM / 4 + 255) / 256, 256, 0, stream>>>(x_b, xb_bf0, NB * CDIM);
    zero_rows_kernel<<<1, 256, 0, stream>>>(xa_bf0, xb_bf0, xa_bf1, xb_bf1);

    hipMemsetAsync(bcnt, 0, 3 * NBUCK * sizeof(int), stream);
    dim3 cgrid((EDGES + 4095) / 4096, 3);
    bucket_count_kernel<<<cgrid, 256, 0, stream>>>(e_ab, e_ba, e_aa, bcnt);
    bucket_scan_kernel<<<1, 32, 0, stream>>>(bcnt, boff, bcur);
    bucket_partition_kernel<<<cgrid, 256, 0, stream>>>(e_ab, e_ba, e_aa, bcur, buf);
    dim3 sgrid(NBUCK, 3);
    bucket_scatter_kernel<<<sgrid, 256, 0, stream>>>(buf, boff, rowptr, col);

    const int* rp_ab = rowptr;
    const int* rp_ba = rowptr + (NN + 1);
    const int* rp_aa = rowptr + 2 * (NN + 1);
    const int* col_ab = col;
    const int* col_ba = col + EDGES;
    const int* col_aa = col + 2 * EDGES;

    const int fgrid = (NN + RROWS - 1) / RROWS;   // 1563

    for (int l = 0; l < 2; l++) {
        const float* xa_cur = (l == 0) ? x_a : xa_buf;
        const float* xb_cur = (l == 0) ? x_b : xb_buf;
        const unsigned short* xa_bf = (l == 0) ? xa_bf0 : xa_bf1;
        const unsigned short* xb_bf = (l == 0) ? xb_bf0 : xb_bf1;
        const unsigned short* Wab = Wbf + (size_t)(l * 3 + 0) * 16384;
        const unsigned short* Wba = Wbf + (size_t)(l * 3 + 1) * 16384;
        const unsigned short* Waa = Wbf + (size_t)(l * 3 + 2) * 16384;
        float* xa_nxt = (l == 0) ? xa_buf : out_xa;
        float* xb_nxt = (l == 0) ? xb_buf : out_xb;
        unsigned short* xa_nbf = (l == 0) ? xa_bf1 : nullptr;
        unsigned short* xb_nbf = (l == 0) ? xb_bf1 : nullptr;

        fuse_b_kernel<<<fgrid, 256, 0, stream>>>(
            xa_bf, xb_cur, rp_ab, col_ab, Wab,
            sbias + (size_t)(l * 3 + 0) * 128,
            lnw + (size_t)(l * 2 + 1) * 128, lnb + (size_t)(l * 2 + 1) * 128,
            xb_nxt, xb_nbf);
        fuse_a_kernel<<<fgrid, 256, 0, stream>>>(
            xb_bf, rp_ba, col_ba, xa_bf, rp_aa, col_aa, xa_cur,
            Wba, Waa,
            sbias + (size_t)(l * 3 + 1) * 128, sbias + (size_t)(l * 3 + 2) * 128,
            lnw + (size_t)(l * 2 + 0) * 128, lnb + (size_t)(l * 2 + 0) * 128,
            xa_nxt, xa_nbf);
    }
}